// Round 1
// baseline (15026.010 us; speedup 1.0000x reference)
//
#include <hip/hip_runtime.h>
#include <stdint.h>

// LSTM autoencoder: B=64, T=256, P=128, H=512, LAT=128
// out = [x_hat (64*256*128 f32), z (64*128 f32)]

typedef unsigned short u16;
typedef unsigned int u32;
typedef float f32x4 __attribute__((ext_vector_type(4)));
typedef __bf16 bf16x8 __attribute__((ext_vector_type(8)));
typedef unsigned int u32x4 __attribute__((ext_vector_type(4)));

__device__ __forceinline__ u16 f2bf(float f) {
  u32 u = __builtin_bit_cast(u32, f);
  u += 0x7FFFu + ((u >> 16) & 1u);
  return (u16)(u >> 16);
}
__device__ __forceinline__ float bf2f(u16 h) {
  return __builtin_bit_cast(float, (u32)h << 16);
}
__device__ __forceinline__ bf16x8 ld8(const u16* p) {
  u32x4 v = *(const u32x4*)p;
  return __builtin_bit_cast(bf16x8, v);
}
__device__ __forceinline__ float sigf(float x) { return 1.f / (1.f + __expf(-x)); }
__device__ __forceinline__ float tanhx(float x) {
  x = fminf(fmaxf(x, -15.f), 15.f);
  float e = __expf(2.f * x);
  return (e - 1.f) / (e + 1.f);
}

// ---- inter-block barrier (groups of nb blocks, all resident) ----
// bar[0] = arrive count, bar[1] = generation
__device__ __forceinline__ void group_barrier(u32* bar, u32 nb) {
  __syncthreads();  // all waves' stores drained (vmcnt) before arrival
  if (threadIdx.x == 0) {
    u32 gen = __hip_atomic_load(bar + 1, __ATOMIC_RELAXED, __HIP_MEMORY_SCOPE_AGENT);
    u32 prev = __hip_atomic_fetch_add(bar, 1u, __ATOMIC_ACQ_REL, __HIP_MEMORY_SCOPE_AGENT);
    if (prev == nb - 1u) {
      __hip_atomic_store(bar, 0u, __ATOMIC_RELAXED, __HIP_MEMORY_SCOPE_AGENT);
      __hip_atomic_store(bar + 1, gen + 1u, __ATOMIC_RELEASE, __HIP_MEMORY_SCOPE_AGENT);
    } else {
      while (__hip_atomic_load(bar + 1, __ATOMIC_ACQUIRE, __HIP_MEMORY_SCOPE_AGENT) == gen) {
        __builtin_amdgcn_s_sleep(1);
      }
    }
  }
  __syncthreads();
  __threadfence();  // every wave: invalidate stale L1/L2 before reading peers' h
}

// ---- small prep kernels ----
__global__ void k_prep_x(const float* __restrict__ x, const float* __restrict__ st,
                         u16* __restrict__ Ax, u16* __restrict__ Axs, int n) {
  int i = blockIdx.x * 256 + threadIdx.x;
  if (i >= n) return;
  Ax[i] = f2bf(x[i]);
  int col = i & 127;
  int t = (i >> 7) & 255;
  float v = (t == 0) ? st[col] : x[i - 128];
  Axs[i] = f2bf(v);
}

__global__ void k_cvt(const float* __restrict__ in, u16* __restrict__ out, int n) {
  int i = blockIdx.x * 256 + threadIdx.x;
  if (i < n) out[i] = f2bf(in[i]);
}

// ---- bulk GEMM: C[M][N] = A[M][K] @ B'[N][K]^T + bias, bf16 in, fp32 acc ----
// BM=BN=128, BK=64, 4 waves each 64x64. sig=0: bf16 store; sig=1: f32 sigmoid store.
__global__ __launch_bounds__(256) void k_gemm_bt(
    const u16* __restrict__ A, const u16* __restrict__ B, const float* __restrict__ bias,
    u16* __restrict__ Cb, float* __restrict__ Cf, int M, int N, int K, int sig) {
  __shared__ __align__(16) u16 As[128 * 64];
  __shared__ __align__(16) u16 Bs[128 * 64];
  const int m0 = blockIdx.x * 128, n0 = blockIdx.y * 128;
  const int tid = threadIdx.x, lane = tid & 63, wave = tid >> 6;
  const int wm = wave >> 1, wn = wave & 1;

  f32x4 acc[4][4];
#pragma unroll
  for (int i = 0; i < 4; ++i)
#pragma unroll
    for (int j = 0; j < 4; ++j) acc[i][j] = (f32x4){0.f, 0.f, 0.f, 0.f};

  const int nkt = K >> 6;
  for (int kt = 0; kt < nkt; ++kt) {
#pragma unroll
    for (int i = 0; i < 4; ++i) {
      int ch = tid + (i << 8);        // 0..1023
      int row = ch >> 3, k8 = ch & 7; // row 0..127, 8-elem chunk
      int dst = row * 128 + ((k8 * 16) ^ ((row & 7) << 4));
      u32x4 va = *(const u32x4*)(A + (size_t)(m0 + row) * K + kt * 64 + k8 * 8);
      *(u32x4*)((char*)As + dst) = va;
      u32x4 vb = *(const u32x4*)(B + (size_t)(n0 + row) * K + kt * 64 + k8 * 8);
      *(u32x4*)((char*)Bs + dst) = vb;
    }
    __syncthreads();
#pragma unroll
    for (int kk = 0; kk < 2; ++kk) {
      int kb = kk * 64 + ((lane >> 4) << 4);  // byte offset of k0 within row
      bf16x8 afr[4], bfr[4];
#pragma unroll
      for (int i = 0; i < 4; ++i) {
        int ra = wm * 64 + i * 16 + (lane & 15);
        afr[i] = ld8((const u16*)((const char*)As + ra * 128 + (kb ^ ((ra & 7) << 4))));
        int rb = wn * 64 + i * 16 + (lane & 15);
        bfr[i] = ld8((const u16*)((const char*)Bs + rb * 128 + (kb ^ ((rb & 7) << 4))));
      }
#pragma unroll
      for (int i = 0; i < 4; ++i)
#pragma unroll
        for (int j = 0; j < 4; ++j)
          acc[i][j] = __builtin_amdgcn_mfma_f32_16x16x32_bf16(afr[i], bfr[j], acc[i][j], 0, 0, 0);
    }
    __syncthreads();
  }
#pragma unroll
  for (int i = 0; i < 4; ++i) {
#pragma unroll
    for (int j = 0; j < 4; ++j) {
      int col = n0 + wn * 64 + j * 16 + (lane & 15);
      float bv = bias ? bias[col] : 0.f;
#pragma unroll
      for (int r = 0; r < 4; ++r) {
        int row = m0 + wm * 64 + i * 16 + ((lane >> 4) << 2) + r;
        float v = acc[i][j][r] + bv;
        if (sig) Cf[(size_t)row * N + col] = 1.f / (1.f + __expf(-v));
        else     Cb[(size_t)row * N + col] = f2bf(v);
      }
    }
  }
}

// ---- persistent recurrent LSTM kernel ----
// grid = ndir*64 blocks; per dir: 4 batch-groups(16 rows) x 16 col-blocks(32 h-cols).
// Whh slice (512x128) lives in LDS; h exchanged via global, 16-block barrier per step.
struct RecParams {
  const u16* xW0; const u16* xW1;      // bf16 [64][256][2048] (bias included)
  const float* Whh0; const float* Whh1;// fp32 [2048][512]
  const float* h0;                     // fp32 [64][512] or null
  u16* seq0; u16* seq1;                // bf16 seq out or null
  int seq_stride; int coloff0; int coloff1;
  int rev0; int rev1;                  // time-reversal for xW read AND seq write
  float* hfin0; float* hfin1; int hfin_stride;
  u16* hbuf;                           // [dir*4+g][2][16][512] bf16
  u32* bar;                            // barrier slots, 64 u32 stride per group
};

__global__ __launch_bounds__(256, 1) void k_lstm_rec(RecParams p) {
  const int dir = blockIdx.x >> 6;
  const int rb = blockIdx.x & 63;
  const int g = rb >> 4;   // batch group
  const int c = rb & 15;   // col block
  const int tid = threadIdx.x;
  const int lane = tid & 63;
  const int wave = tid >> 6;

  const u16* __restrict__ xW = dir ? p.xW1 : p.xW0;
  const float* __restrict__ Whh = dir ? p.Whh1 : p.Whh0;
  u16* seq = dir ? p.seq1 : p.seq0;
  const int coloff = dir ? p.coloff1 : p.coloff0;
  const int rev = dir ? p.rev1 : p.rev0;
  float* hfin = dir ? p.hfin1 : p.hfin0;
  u16* hb = p.hbuf + (size_t)(dir * 4 + g) * 16384;
  u32* bar = p.bar + (dir * 4 + g) * 64;

  __shared__ __align__(16) u16 Wlds[64][128][8]; // (k,n) at [k>>3][n][k&7]; n = gate*32+jl
  __shared__ float gbuf[4][16][32];
  __shared__ float cbuf[512];

  // fill Whh slice: n -> global g-row = gate*512 + c*32 + jl
  for (int e = tid; e < 65536; e += 256) {
    int n = e >> 9;
    int k = e & 511;
    int grow = ((n >> 5) << 9) | (c << 5) | (n & 31);
    Wlds[k >> 3][n][k & 7] = f2bf(Whh[(size_t)grow * 512 + k]);
  }
  // init c and h0 slice
  for (int e = tid; e < 512; e += 256) {
    cbuf[e] = 0.f;
    int row = e >> 5, jl = e & 31;
    float hv = p.h0 ? p.h0[(size_t)(g * 16 + row) * 512 + (c << 5) + jl] : 0.f;
    hb[row * 512 + (c << 5) + jl] = f2bf(hv);
  }
  group_barrier(bar, 16);

  const int arow = lane & 15;
  const int kg = lane >> 4;

  for (int t = 0; t < 256; ++t) {
    const u16* hcur = hb + (t & 1) * 8192;
    u16* hnxt = hb + ((t + 1) & 1) * 8192;

    // preload all A fragments (h rows, bf16) from global
    bf16x8 af[16];
#pragma unroll
    for (int kk = 0; kk < 16; ++kk) {
      int k0 = (kk << 5) + (kg << 3);
      af[kk] = ld8(hcur + arow * 512 + k0);
    }
    f32x4 acc0 = {0.f, 0.f, 0.f, 0.f};
    f32x4 acc1 = {0.f, 0.f, 0.f, 0.f};
#pragma unroll
    for (int kk = 0; kk < 16; ++kk) {
      int k0 = (kk << 5) + (kg << 3);
      const u16* bp = &Wlds[k0 >> 3][(wave << 5) + arow][0];
      bf16x8 b0 = ld8(bp);
      bf16x8 b1 = ld8(bp + 128); // +16 columns
      acc0 = __builtin_amdgcn_mfma_f32_16x16x32_bf16(af[kk], b0, acc0, 0, 0, 0);
      acc1 = __builtin_amdgcn_mfma_f32_16x16x32_bf16(af[kk], b1, acc1, 0, 0, 0);
    }
    // epilogue: add xW, stash gates in LDS. wave == gate index.
    const int t_eff = rev ? 255 - t : t;
#pragma unroll
    for (int r4 = 0; r4 < 4; ++r4) {
      int row = ((lane >> 4) << 2) + r4;
      const u16* xwp = xW + (((size_t)((g * 16 + row) * 256 + t_eff)) << 11) + (wave << 9) + (c << 5);
      gbuf[wave][row][arow] = acc0[r4] + bf2f(xwp[arow]);
      gbuf[wave][row][arow + 16] = acc1[r4] + bf2f(xwp[arow + 16]);
    }
    __syncthreads();
    // gate math + h/c update (block-local c; h slice published)
    for (int e = tid; e < 512; e += 256) {
      int row = e >> 5, jl = e & 31;
      float iv = gbuf[0][row][jl];
      float fv = gbuf[1][row][jl];
      float gv = gbuf[2][row][jl];
      float ov = gbuf[3][row][jl];
      float cc = sigf(fv) * cbuf[e] + sigf(iv) * tanhx(gv);
      float hh = sigf(ov) * tanhx(cc);
      cbuf[e] = cc;
      u16 hu = f2bf(hh);
      hnxt[row * 512 + (c << 5) + jl] = hu;
      if (seq)
        seq[(size_t)((g * 16 + row) * 256 + t_eff) * p.seq_stride + coloff + (c << 5) + jl] = hu;
      if (hfin && t == 255)
        hfin[(size_t)(g * 16 + row) * p.hfin_stride + (c << 5) + jl] = hh;
    }
    group_barrier(bar, 16);
  }
}

// ---- tiny heads ----
__global__ void k_enc_head(const float* __restrict__ hcat, const float* __restrict__ W,
                           const float* __restrict__ b, float* __restrict__ zws,
                           float* __restrict__ zout) {
  int bi = blockIdx.x, j = threadIdx.x; // 64 blocks x 128 threads
  const float* h = hcat + bi * 1024;
  const float* w = W + j * 1024;
  float s = b[j];
  for (int k = 0; k < 1024; ++k) s += h[k] * w[k];
  zws[bi * 128 + j] = s;
  zout[bi * 128 + j] = s;
}

__global__ void k_dec_head(const float* __restrict__ z, const float* __restrict__ W,
                           const float* __restrict__ b, float* __restrict__ h0d) {
  int bi = blockIdx.x, j = threadIdx.x; // 64 blocks x 512 threads
  const float* zz = z + bi * 128;
  const float* w = W + j * 128;
  float s = b[j];
  for (int k = 0; k < 128; ++k) s += zz[k] * w[k];
  h0d[bi * 512 + j] = s;
}

extern "C" void kernel_launch(void* const* d_in, const int* in_sizes, int n_in,
                              void* d_out, int out_size, void* d_ws, size_t ws_size,
                              hipStream_t stream) {
  (void)in_sizes; (void)n_in; (void)out_size;
  const float* x        = (const float*)d_in[0];
  const float* e0f_Wih  = (const float*)d_in[1];
  const float* e0f_Whh  = (const float*)d_in[2];
  const float* e0f_b    = (const float*)d_in[3];
  const float* e0b_Wih  = (const float*)d_in[4];
  const float* e0b_Whh  = (const float*)d_in[5];
  const float* e0b_b    = (const float*)d_in[6];
  const float* e1f_Wih  = (const float*)d_in[7];
  const float* e1f_Whh  = (const float*)d_in[8];
  const float* e1f_b    = (const float*)d_in[9];
  const float* e1b_Wih  = (const float*)d_in[10];
  const float* e1b_Whh  = (const float*)d_in[11];
  const float* e1b_b    = (const float*)d_in[12];
  const float* enc_fc_W = (const float*)d_in[13];
  const float* enc_fc_b = (const float*)d_in[14];
  const float* dec_fc_W = (const float*)d_in[15];
  const float* dec_fc_b = (const float*)d_in[16];
  const float* start_tk = (const float*)d_in[17];
  const float* d0_Wih   = (const float*)d_in[18];
  const float* d0_Whh   = (const float*)d_in[19];
  const float* d0_b     = (const float*)d_in[20];
  const float* d1_Wih   = (const float*)d_in[21];
  const float* d1_Whh   = (const float*)d_in[22];
  const float* d1_b     = (const float*)d_in[23];
  const float* out_W    = (const float*)d_in[24];
  const float* out_b    = (const float*)d_in[25];

  uintptr_t base = (uintptr_t)d_ws;
  size_t off = 0;
  auto carve = [&](size_t bytes) -> void* {
    off = (off + 255) & ~(size_t)255;
    void* p = (void*)(base + off);
    off += bytes;
    return p;
  };
  u16* Ax     = (u16*)carve((size_t)2097152 * 2);
  u16* Axs    = (u16*)carve((size_t)2097152 * 2);
  u16* Wb_e0f = (u16*)carve((size_t)262144 * 2);
  u16* Wb_e0b = (u16*)carve((size_t)262144 * 2);
  u16* Wb_d0  = (u16*)carve((size_t)262144 * 2);
  u16* Wb_e1f = (u16*)carve((size_t)2097152 * 2);
  u16* Wb_e1b = (u16*)carve((size_t)2097152 * 2);
  u16* Wb_d1  = (u16*)carve((size_t)1048576 * 2);
  u16* Wb_out = (u16*)carve((size_t)65536 * 2);
  u16* slot0  = (u16*)carve((size_t)16384 * 2048 * 2);
  u16* slot1  = (u16*)carve((size_t)16384 * 2048 * 2);
  u16* l0     = (u16*)carve((size_t)16384 * 1024 * 2);
  u16* o0     = (u16*)carve((size_t)16384 * 512 * 2);
  u16* o1     = (u16*)carve((size_t)16384 * 512 * 2);
  u16* hbuf   = (u16*)carve((size_t)131072 * 2);
  float* hcat = (float*)carve((size_t)65536 * 4);
  float* zws  = (float*)carve((size_t)8192 * 4);
  float* h0d  = (float*)carve((size_t)32768 * 4);
  u32* bar    = (u32*)carve(2048);
  if (off > ws_size) return;  // workspace too small: fail loudly via absmax

  (void)hipMemsetAsync(bar, 0, 2048, stream);

  k_prep_x<<<8192, 256, 0, stream>>>(x, start_tk, Ax, Axs, 2097152);
  k_cvt<<<1024, 256, 0, stream>>>(e0f_Wih, Wb_e0f, 262144);
  k_cvt<<<1024, 256, 0, stream>>>(e0b_Wih, Wb_e0b, 262144);
  k_cvt<<<1024, 256, 0, stream>>>(d0_Wih, Wb_d0, 262144);
  k_cvt<<<8192, 256, 0, stream>>>(e1f_Wih, Wb_e1f, 2097152);
  k_cvt<<<8192, 256, 0, stream>>>(e1b_Wih, Wb_e1b, 2097152);
  k_cvt<<<4096, 256, 0, stream>>>(d1_Wih, Wb_d1, 1048576);
  k_cvt<<<256, 256, 0, stream>>>(out_W, Wb_out, 65536);

  // encoder layer 0: projections then bidirectional recurrence -> l0
  k_gemm_bt<<<dim3(128, 16), 256, 0, stream>>>(Ax, Wb_e0f, e0f_b, slot0, nullptr, 16384, 2048, 128, 0);
  k_gemm_bt<<<dim3(128, 16), 256, 0, stream>>>(Ax, Wb_e0b, e0b_b, slot1, nullptr, 16384, 2048, 128, 0);
  {
    RecParams rp{};
    rp.xW0 = slot0; rp.xW1 = slot1; rp.Whh0 = e0f_Whh; rp.Whh1 = e0b_Whh;
    rp.h0 = nullptr;
    rp.seq0 = l0; rp.seq1 = l0; rp.seq_stride = 1024; rp.coloff0 = 0; rp.coloff1 = 512;
    rp.rev0 = 0; rp.rev1 = 1;
    rp.hfin0 = nullptr; rp.hfin1 = nullptr; rp.hfin_stride = 0;
    rp.hbuf = hbuf; rp.bar = bar;
    k_lstm_rec<<<128, 256, 0, stream>>>(rp);
  }
  // encoder layer 1: projections then recurrence (final h only) -> hcat
  k_gemm_bt<<<dim3(128, 16), 256, 0, stream>>>(l0, Wb_e1f, e1f_b, slot0, nullptr, 16384, 2048, 1024, 0);
  k_gemm_bt<<<dim3(128, 16), 256, 0, stream>>>(l0, Wb_e1b, e1b_b, slot1, nullptr, 16384, 2048, 1024, 0);
  {
    RecParams rp{};
    rp.xW0 = slot0; rp.xW1 = slot1; rp.Whh0 = e1f_Whh; rp.Whh1 = e1b_Whh;
    rp.h0 = nullptr;
    rp.seq0 = nullptr; rp.seq1 = nullptr; rp.seq_stride = 0; rp.coloff0 = 0; rp.coloff1 = 0;
    rp.rev0 = 0; rp.rev1 = 1;
    rp.hfin0 = hcat; rp.hfin1 = hcat + 512; rp.hfin_stride = 1024;
    rp.hbuf = hbuf; rp.bar = bar;
    k_lstm_rec<<<128, 256, 0, stream>>>(rp);
  }
  // bottleneck: z (to out + ws), h0d
  k_enc_head<<<64, 128, 0, stream>>>(hcat, enc_fc_W, enc_fc_b, zws, ((float*)d_out) + 2097152);
  k_dec_head<<<64, 512, 0, stream>>>(zws, dec_fc_W, dec_fc_b, h0d);
  // decoder layer 0
  k_gemm_bt<<<dim3(128, 16), 256, 0, stream>>>(Axs, Wb_d0, d0_b, slot0, nullptr, 16384, 2048, 128, 0);
  {
    RecParams rp{};
    rp.xW0 = slot0; rp.xW1 = nullptr; rp.Whh0 = d0_Whh; rp.Whh1 = nullptr;
    rp.h0 = h0d;
    rp.seq0 = o0; rp.seq1 = nullptr; rp.seq_stride = 512; rp.coloff0 = 0; rp.coloff1 = 0;
    rp.rev0 = 0; rp.rev1 = 0;
    rp.hfin0 = nullptr; rp.hfin1 = nullptr; rp.hfin_stride = 0;
    rp.hbuf = hbuf; rp.bar = bar;
    k_lstm_rec<<<64, 256, 0, stream>>>(rp);
  }
  // decoder layer 1
  k_gemm_bt<<<dim3(128, 16), 256, 0, stream>>>(o0, Wb_d1, d1_b, slot1, nullptr, 16384, 2048, 512, 0);
  {
    RecParams rp{};
    rp.xW0 = slot1; rp.xW1 = nullptr; rp.Whh0 = d1_Whh; rp.Whh1 = nullptr;
    rp.h0 = h0d;
    rp.seq0 = o1; rp.seq1 = nullptr; rp.seq_stride = 512; rp.coloff0 = 0; rp.coloff1 = 0;
    rp.rev0 = 0; rp.rev1 = 0;
    rp.hfin0 = nullptr; rp.hfin1 = nullptr; rp.hfin_stride = 0;
    rp.hbuf = hbuf; rp.bar = bar;
    k_lstm_rec<<<64, 256, 0, stream>>>(rp);
  }
  // output projection + sigmoid -> x_hat
  k_gemm_bt<<<dim3(128, 1), 256, 0, stream>>>(o1, Wb_out, out_b, nullptr, (float*)d_out, 16384, 128, 512, 1);
}

// Round 2
// 10387.555 us; speedup vs baseline: 1.4465x; 1.4465x over previous
//
#include <hip/hip_runtime.h>
#include <stdint.h>

// LSTM autoencoder: B=64, T=256, P=128, H=512, LAT=128
// out = [x_hat (64*256*128 f32), z (64*128 f32)]

typedef unsigned short u16;
typedef unsigned int u32;
typedef float f32x4 __attribute__((ext_vector_type(4)));
typedef __bf16 bf16x8 __attribute__((ext_vector_type(8)));
typedef unsigned int u32x4 __attribute__((ext_vector_type(4)));

#define AT_LD(p) __hip_atomic_load((p), __ATOMIC_RELAXED, __HIP_MEMORY_SCOPE_AGENT)
#define AT_ST(p, v) __hip_atomic_store((p), (v), __ATOMIC_RELAXED, __HIP_MEMORY_SCOPE_AGENT)

__device__ __forceinline__ u16 f2bf(float f) {
  u32 u = __builtin_bit_cast(u32, f);
  u += 0x7FFFu + ((u >> 16) & 1u);
  return (u16)(u >> 16);
}
__device__ __forceinline__ float bf2f(u16 h) {
  return __builtin_bit_cast(float, (u32)h << 16);
}
__device__ __forceinline__ bf16x8 ld8(const u16* p) {
  u32x4 v = *(const u32x4*)p;
  return __builtin_bit_cast(bf16x8, v);
}
__device__ __forceinline__ float sigf(float x) { return 1.f / (1.f + __expf(-x)); }
__device__ __forceinline__ float tanhx(float x) {
  x = fminf(fmaxf(x, -15.f), 15.f);
  float e = __expf(2.f * x);
  return (e - 1.f) / (e + 1.f);
}

// ---- fence-free inter-block barrier: 16 participants, monotonic counter ----
// bar[0] = cumulative arrivals, bar[1] = generation. All accesses relaxed
// agent-scope atomics (sc1): data h-stores are sc1 too, acked at the coherence
// point before s_barrier releases (per-wave vmcnt(0) drain) -> no fences needed.
__device__ __forceinline__ void group_barrier(u32* bar) {
  asm volatile("s_waitcnt vmcnt(0)" ::: "memory");
  __syncthreads();
  if (threadIdx.x == 0) {
    u32 gen = AT_LD(bar + 1);
    u32 prev = __hip_atomic_fetch_add(bar, 1u, __ATOMIC_RELAXED, __HIP_MEMORY_SCOPE_AGENT);
    if (prev == gen * 16u + 15u) {
      AT_ST(bar + 1, gen + 1u);
    } else {
      while (AT_LD(bar + 1) == gen) __builtin_amdgcn_s_sleep(1);
    }
  }
  __syncthreads();
}

// ---- small prep kernels ----
__global__ void k_prep_x(const float* __restrict__ x, const float* __restrict__ st,
                         u16* __restrict__ Ax, u16* __restrict__ Axs, int n) {
  int i = blockIdx.x * 256 + threadIdx.x;
  if (i >= n) return;
  Ax[i] = f2bf(x[i]);
  int col = i & 127;
  int t = (i >> 7) & 255;
  float v = (t == 0) ? st[col] : x[i - 128];
  Axs[i] = f2bf(v);
}

__global__ void k_cvt(const float* __restrict__ in, u16* __restrict__ out, int n) {
  int i = blockIdx.x * 256 + threadIdx.x;
  if (i < n) out[i] = f2bf(in[i]);
}

// ---- bulk GEMM: C[M][N] = A[M][K] @ B'[N][K]^T + bias, bf16 in, fp32 acc ----
__global__ __launch_bounds__(256) void k_gemm_bt(
    const u16* __restrict__ A, const u16* __restrict__ B, const float* __restrict__ bias,
    u16* __restrict__ Cb, float* __restrict__ Cf, int M, int N, int K, int sig) {
  __shared__ __align__(16) u16 As[128 * 64];
  __shared__ __align__(16) u16 Bs[128 * 64];
  const int m0 = blockIdx.x * 128, n0 = blockIdx.y * 128;
  const int tid = threadIdx.x, lane = tid & 63, wave = tid >> 6;
  const int wm = wave >> 1, wn = wave & 1;

  f32x4 acc[4][4];
#pragma unroll
  for (int i = 0; i < 4; ++i)
#pragma unroll
    for (int j = 0; j < 4; ++j) acc[i][j] = (f32x4){0.f, 0.f, 0.f, 0.f};

  const int nkt = K >> 6;
  for (int kt = 0; kt < nkt; ++kt) {
#pragma unroll
    for (int i = 0; i < 4; ++i) {
      int ch = tid + (i << 8);
      int row = ch >> 3, k8 = ch & 7;
      int dst = row * 128 + ((k8 * 16) ^ ((row & 7) << 4));
      u32x4 va = *(const u32x4*)(A + (size_t)(m0 + row) * K + kt * 64 + k8 * 8);
      *(u32x4*)((char*)As + dst) = va;
      u32x4 vb = *(const u32x4*)(B + (size_t)(n0 + row) * K + kt * 64 + k8 * 8);
      *(u32x4*)((char*)Bs + dst) = vb;
    }
    __syncthreads();
#pragma unroll
    for (int kk = 0; kk < 2; ++kk) {
      int kb = kk * 64 + ((lane >> 4) << 4);
      bf16x8 afr[4], bfr[4];
#pragma unroll
      for (int i = 0; i < 4; ++i) {
        int ra = wm * 64 + i * 16 + (lane & 15);
        afr[i] = ld8((const u16*)((const char*)As + ra * 128 + (kb ^ ((ra & 7) << 4))));
        int rb = wn * 64 + i * 16 + (lane & 15);
        bfr[i] = ld8((const u16*)((const char*)Bs + rb * 128 + (kb ^ ((rb & 7) << 4))));
      }
#pragma unroll
      for (int i = 0; i < 4; ++i)
#pragma unroll
        for (int j = 0; j < 4; ++j)
          acc[i][j] = __builtin_amdgcn_mfma_f32_16x16x32_bf16(afr[i], bfr[j], acc[i][j], 0, 0, 0);
    }
    __syncthreads();
  }
#pragma unroll
  for (int i = 0; i < 4; ++i) {
#pragma unroll
    for (int j = 0; j < 4; ++j) {
      int col = n0 + wn * 64 + j * 16 + (lane & 15);
      float bv = bias ? bias[col] : 0.f;
#pragma unroll
      for (int r = 0; r < 4; ++r) {
        int row = m0 + wm * 64 + i * 16 + ((lane >> 4) << 2) + r;
        float v = acc[i][j][r] + bv;
        if (sig) Cf[(size_t)row * N + col] = 1.f / (1.f + __expf(-v));
        else     Cb[(size_t)row * N + col] = f2bf(v);
      }
    }
  }
}

// ---- persistent recurrent LSTM kernel ----
// Per chain (dir,group of 16 batch rows): 16 col-blocks x 32 h-cols.
// Whh slice (bf16, pre-converted) lives in LDS; h exchanged via relaxed
// agent-scope (sc1) atomics; 16-block fence-free barrier per step.
// Block remap: chain = blockIdx%8 (encoder) so a chain's blocks share an XCD
// under round-robin placement (perf heuristic only).
struct RecParams {
  const u16* xW0; const u16* xW1;      // bf16 [64][256][2048] (bias included)
  const u16* Whh0; const u16* Whh1;    // bf16 [2048][512]
  const float* h0;                     // fp32 [64][512] or null
  u16* seq0; u16* seq1;                // bf16 seq out or null
  int seq_stride; int coloff0; int coloff1;
  int rev0; int rev1;
  float* hfin0; float* hfin1; int hfin_stride;
  u16* hbuf;                           // [chain][2][16][512] bf16
  u32* bar;                            // 64 u32 stride per chain
  int spread2;                         // decoder: stride-2 chain slots
};

__global__ __launch_bounds__(256, 1) void k_lstm_rec(RecParams p) {
  const int bid = blockIdx.x;
  int chain;
  if (p.spread2) {
    if (bid & 1) return;          // dummy block (XCD spacing), exits immediately
    chain = (bid & 7) >> 1;       // 4 chains on even slots
  } else {
    chain = bid & 7;              // 8 chains
  }
  const int c = bid >> 3;         // col-block 0..15
  const int dir = p.spread2 ? 0 : (chain >> 2);
  const int g = p.spread2 ? chain : (chain & 3);
  const int tid = threadIdx.x;
  const int lane = tid & 63;
  const int wave = tid >> 6;

  const u16* __restrict__ xW = dir ? p.xW1 : p.xW0;
  const u16* __restrict__ Whh = dir ? p.Whh1 : p.Whh0;
  u16* seq = dir ? p.seq1 : p.seq0;
  const int coloff = dir ? p.coloff1 : p.coloff0;
  const int rev = dir ? p.rev1 : p.rev0;
  float* hfin = dir ? p.hfin1 : p.hfin0;
  u16* hb = p.hbuf + (size_t)chain * 16384;
  u32* bar = p.bar + chain * 64;

  __shared__ __align__(16) u16 Wlds[64][128][8]; // (k,n) at [k>>3][n][k&7]; n=gate*32+jl
  __shared__ float gbuf[4][16][32];
  __shared__ float cbuf[512];

  // fill Whh slice from pre-converted bf16 (16B vector copies)
  for (int e = tid; e < 8192; e += 256) {
    int n = e >> 6, k8 = e & 63;
    int grow = ((n >> 5) << 9) | (c << 5) | (n & 31);
    u32x4 v = *(const u32x4*)(Whh + (size_t)grow * 512 + k8 * 8);
    *(u32x4*)(&Wlds[k8][n][0]) = v;
  }
  // init c; publish h0 slice via sc1 atomics (visible to peers' sc1 loads)
  for (int e = tid; e < 512; e += 256) cbuf[e] = 0.f;
  {
    int row = tid >> 4, q = tid & 15;
    float h0a = 0.f, h0b = 0.f;
    if (p.h0) {
      h0a = p.h0[(size_t)(g * 16 + row) * 512 + (c << 5) + 2 * q];
      h0b = p.h0[(size_t)(g * 16 + row) * 512 + (c << 5) + 2 * q + 1];
    }
    u32 pk = (u32)f2bf(h0a) | ((u32)f2bf(h0b) << 16);
    AT_ST((u32*)hb + row * 256 + (c << 4) + q, pk);
  }
  group_barrier(bar);

  const int arow = lane & 15;
  const int kg = lane >> 4;

  for (int t = 0; t < 256; ++t) {
    const u32* hcur32 = (const u32*)hb + (t & 1) * 4096;
    u32* hnxt32 = (u32*)hb + ((t + 1) & 1) * 4096;
    const int t_eff = rev ? 255 - t : t;

    // prefetch xW early (plain loads; overlap with h loads + MFMA)
    float xwv[4][2];
#pragma unroll
    for (int r4 = 0; r4 < 4; ++r4) {
      int row = (kg << 2) + r4;
      const u16* xwp = xW + (((size_t)((g * 16 + row) * 256 + t_eff)) << 11) + (wave << 9) + (c << 5);
      xwv[r4][0] = bf2f(xwp[arow]);
      xwv[r4][1] = bf2f(xwp[arow + 16]);
    }

    // load all A fragments (peers' h) via sc1 atomic dwords
    bf16x8 af[16];
#pragma unroll
    for (int kk = 0; kk < 16; ++kk) {
      int k0 = (kk << 5) + (kg << 3);
      const u32* hp = hcur32 + arow * 256 + (k0 >> 1);
      u32x4 v;
      v.x = AT_LD(hp + 0);
      v.y = AT_LD(hp + 1);
      v.z = AT_LD(hp + 2);
      v.w = AT_LD(hp + 3);
      af[kk] = __builtin_bit_cast(bf16x8, v);
    }

    f32x4 acc0 = {0.f, 0.f, 0.f, 0.f};
    f32x4 acc1 = {0.f, 0.f, 0.f, 0.f};
#pragma unroll
    for (int kk = 0; kk < 16; ++kk) {
      int k0 = (kk << 5) + (kg << 3);
      const u16* bp = &Wlds[k0 >> 3][(wave << 5) + arow][0];
      bf16x8 b0 = ld8(bp);
      bf16x8 b1 = ld8(bp + 128);
      acc0 = __builtin_amdgcn_mfma_f32_16x16x32_bf16(af[kk], b0, acc0, 0, 0, 0);
      acc1 = __builtin_amdgcn_mfma_f32_16x16x32_bf16(af[kk], b1, acc1, 0, 0, 0);
    }
    // publish gates (wave == gate index)
#pragma unroll
    for (int r4 = 0; r4 < 4; ++r4) {
      int row = (kg << 2) + r4;
      gbuf[wave][row][arow] = acc0[r4] + xwv[r4][0];
      gbuf[wave][row][arow + 16] = acc1[r4] + xwv[r4][1];
    }
    __syncthreads();
    // gate math: one thread per (row, col-pair); c block-local, h via sc1
    {
      int row = tid >> 4, q = tid & 15;
      int j0 = 2 * q;
      float i0 = gbuf[0][row][j0], i1 = gbuf[0][row][j0 + 1];
      float f0 = gbuf[1][row][j0], f1 = gbuf[1][row][j0 + 1];
      float g0 = gbuf[2][row][j0], g1 = gbuf[2][row][j0 + 1];
      float o0 = gbuf[3][row][j0], o1 = gbuf[3][row][j0 + 1];
      int ci = row * 32 + j0;
      float cc0 = sigf(f0) * cbuf[ci] + sigf(i0) * tanhx(g0);
      float cc1 = sigf(f1) * cbuf[ci + 1] + sigf(i1) * tanhx(g1);
      cbuf[ci] = cc0;
      cbuf[ci + 1] = cc1;
      float hh0 = sigf(o0) * tanhx(cc0);
      float hh1 = sigf(o1) * tanhx(cc1);
      u32 pk = (u32)f2bf(hh0) | ((u32)f2bf(hh1) << 16);
      AT_ST(hnxt32 + row * 256 + (c << 4) + q, pk);
      if (seq)
        *(u32*)(seq + (size_t)((g * 16 + row) * 256 + t_eff) * p.seq_stride + coloff + (c << 5) + j0) = pk;
      if (hfin && t == 255) {
        hfin[(size_t)(g * 16 + row) * p.hfin_stride + (c << 5) + j0] = hh0;
        hfin[(size_t)(g * 16 + row) * p.hfin_stride + (c << 5) + j0 + 1] = hh1;
      }
    }
    group_barrier(bar);
  }
}

// ---- tiny heads ----
__global__ void k_enc_head(const float* __restrict__ hcat, const float* __restrict__ W,
                           const float* __restrict__ b, float* __restrict__ zws,
                           float* __restrict__ zout) {
  int bi = blockIdx.x, j = threadIdx.x;
  const float* h = hcat + bi * 1024;
  const float* w = W + j * 1024;
  float s = b[j];
  for (int k = 0; k < 1024; ++k) s += h[k] * w[k];
  zws[bi * 128 + j] = s;
  zout[bi * 128 + j] = s;
}

__global__ void k_dec_head(const float* __restrict__ z, const float* __restrict__ W,
                           const float* __restrict__ b, float* __restrict__ h0d) {
  int bi = blockIdx.x, j = threadIdx.x;
  const float* zz = z + bi * 128;
  const float* w = W + j * 128;
  float s = b[j];
  for (int k = 0; k < 128; ++k) s += zz[k] * w[k];
  h0d[bi * 512 + j] = s;
}

extern "C" void kernel_launch(void* const* d_in, const int* in_sizes, int n_in,
                              void* d_out, int out_size, void* d_ws, size_t ws_size,
                              hipStream_t stream) {
  (void)in_sizes; (void)n_in; (void)out_size;
  const float* x        = (const float*)d_in[0];
  const float* e0f_Wih  = (const float*)d_in[1];
  const float* e0f_Whh  = (const float*)d_in[2];
  const float* e0f_b    = (const float*)d_in[3];
  const float* e0b_Wih  = (const float*)d_in[4];
  const float* e0b_Whh  = (const float*)d_in[5];
  const float* e0b_b    = (const float*)d_in[6];
  const float* e1f_Wih  = (const float*)d_in[7];
  const float* e1f_Whh  = (const float*)d_in[8];
  const float* e1f_b    = (const float*)d_in[9];
  const float* e1b_Wih  = (const float*)d_in[10];
  const float* e1b_Whh  = (const float*)d_in[11];
  const float* e1b_b    = (const float*)d_in[12];
  const float* enc_fc_W = (const float*)d_in[13];
  const float* enc_fc_b = (const float*)d_in[14];
  const float* dec_fc_W = (const float*)d_in[15];
  const float* dec_fc_b = (const float*)d_in[16];
  const float* start_tk = (const float*)d_in[17];
  const float* d0_Wih   = (const float*)d_in[18];
  const float* d0_Whh   = (const float*)d_in[19];
  const float* d0_b     = (const float*)d_in[20];
  const float* d1_Wih   = (const float*)d_in[21];
  const float* d1_Whh   = (const float*)d_in[22];
  const float* d1_b     = (const float*)d_in[23];
  const float* out_W    = (const float*)d_in[24];
  const float* out_b    = (const float*)d_in[25];

  uintptr_t base = (uintptr_t)d_ws;
  size_t off = 0;
  auto carve = [&](size_t bytes) -> void* {
    off = (off + 255) & ~(size_t)255;
    void* p = (void*)(base + off);
    off += bytes;
    return p;
  };
  u16* Ax     = (u16*)carve((size_t)2097152 * 2);
  u16* Axs    = (u16*)carve((size_t)2097152 * 2);
  u16* Wb_e0f = (u16*)carve((size_t)262144 * 2);
  u16* Wb_e0b = (u16*)carve((size_t)262144 * 2);
  u16* Wb_d0  = (u16*)carve((size_t)262144 * 2);
  u16* Wb_e1f = (u16*)carve((size_t)2097152 * 2);
  u16* Wb_e1b = (u16*)carve((size_t)2097152 * 2);
  u16* Wb_d1  = (u16*)carve((size_t)1048576 * 2);
  u16* Wb_out = (u16*)carve((size_t)65536 * 2);
  u16* Wh_e0f = (u16*)carve((size_t)1048576 * 2);
  u16* Wh_e0b = (u16*)carve((size_t)1048576 * 2);
  u16* Wh_e1f = (u16*)carve((size_t)1048576 * 2);
  u16* Wh_e1b = (u16*)carve((size_t)1048576 * 2);
  u16* Wh_d0  = (u16*)carve((size_t)1048576 * 2);
  u16* Wh_d1  = (u16*)carve((size_t)1048576 * 2);
  u16* slot0  = (u16*)carve((size_t)16384 * 2048 * 2);
  u16* slot1  = (u16*)carve((size_t)16384 * 2048 * 2);
  u16* l0     = (u16*)carve((size_t)16384 * 1024 * 2);
  u16* o0     = (u16*)carve((size_t)16384 * 512 * 2);
  u16* o1     = (u16*)carve((size_t)16384 * 512 * 2);
  u16* hbuf   = (u16*)carve((size_t)131072 * 2);
  float* hcat = (float*)carve((size_t)65536 * 4);
  float* zws  = (float*)carve((size_t)8192 * 4);
  float* h0d  = (float*)carve((size_t)32768 * 4);
  u32* bar    = (u32*)carve(2048);
  if (off > ws_size) return;

  (void)hipMemsetAsync(bar, 0, 2048, stream);

  k_prep_x<<<8192, 256, 0, stream>>>(x, start_tk, Ax, Axs, 2097152);
  k_cvt<<<1024, 256, 0, stream>>>(e0f_Wih, Wb_e0f, 262144);
  k_cvt<<<1024, 256, 0, stream>>>(e0b_Wih, Wb_e0b, 262144);
  k_cvt<<<1024, 256, 0, stream>>>(d0_Wih, Wb_d0, 262144);
  k_cvt<<<8192, 256, 0, stream>>>(e1f_Wih, Wb_e1f, 2097152);
  k_cvt<<<8192, 256, 0, stream>>>(e1b_Wih, Wb_e1b, 2097152);
  k_cvt<<<4096, 256, 0, stream>>>(d1_Wih, Wb_d1, 1048576);
  k_cvt<<<256, 256, 0, stream>>>(out_W, Wb_out, 65536);
  k_cvt<<<4096, 256, 0, stream>>>(e0f_Whh, Wh_e0f, 1048576);
  k_cvt<<<4096, 256, 0, stream>>>(e0b_Whh, Wh_e0b, 1048576);
  k_cvt<<<4096, 256, 0, stream>>>(e1f_Whh, Wh_e1f, 1048576);
  k_cvt<<<4096, 256, 0, stream>>>(e1b_Whh, Wh_e1b, 1048576);
  k_cvt<<<4096, 256, 0, stream>>>(d0_Whh, Wh_d0, 1048576);
  k_cvt<<<4096, 256, 0, stream>>>(d1_Whh, Wh_d1, 1048576);

  // encoder layer 0
  k_gemm_bt<<<dim3(128, 16), 256, 0, stream>>>(Ax, Wb_e0f, e0f_b, slot0, nullptr, 16384, 2048, 128, 0);
  k_gemm_bt<<<dim3(128, 16), 256, 0, stream>>>(Ax, Wb_e0b, e0b_b, slot1, nullptr, 16384, 2048, 128, 0);
  {
    RecParams rp{};
    rp.xW0 = slot0; rp.xW1 = slot1; rp.Whh0 = Wh_e0f; rp.Whh1 = Wh_e0b;
    rp.h0 = nullptr;
    rp.seq0 = l0; rp.seq1 = l0; rp.seq_stride = 1024; rp.coloff0 = 0; rp.coloff1 = 512;
    rp.rev0 = 0; rp.rev1 = 1;
    rp.hfin0 = nullptr; rp.hfin1 = nullptr; rp.hfin_stride = 0;
    rp.hbuf = hbuf; rp.bar = bar; rp.spread2 = 0;
    k_lstm_rec<<<128, 256, 0, stream>>>(rp);
  }
  // encoder layer 1
  k_gemm_bt<<<dim3(128, 16), 256, 0, stream>>>(l0, Wb_e1f, e1f_b, slot0, nullptr, 16384, 2048, 1024, 0);
  k_gemm_bt<<<dim3(128, 16), 256, 0, stream>>>(l0, Wb_e1b, e1b_b, slot1, nullptr, 16384, 2048, 1024, 0);
  {
    RecParams rp{};
    rp.xW0 = slot0; rp.xW1 = slot1; rp.Whh0 = Wh_e1f; rp.Whh1 = Wh_e1b;
    rp.h0 = nullptr;
    rp.seq0 = nullptr; rp.seq1 = nullptr; rp.seq_stride = 0; rp.coloff0 = 0; rp.coloff1 = 0;
    rp.rev0 = 0; rp.rev1 = 1;
    rp.hfin0 = hcat; rp.hfin1 = hcat + 512; rp.hfin_stride = 1024;
    rp.hbuf = hbuf; rp.bar = bar; rp.spread2 = 0;
    k_lstm_rec<<<128, 256, 0, stream>>>(rp);
  }
  // bottleneck
  k_enc_head<<<64, 128, 0, stream>>>(hcat, enc_fc_W, enc_fc_b, zws, ((float*)d_out) + 2097152);
  k_dec_head<<<64, 512, 0, stream>>>(zws, dec_fc_W, dec_fc_b, h0d);
  // decoder layer 0
  k_gemm_bt<<<dim3(128, 16), 256, 0, stream>>>(Axs, Wb_d0, d0_b, slot0, nullptr, 16384, 2048, 128, 0);
  {
    RecParams rp{};
    rp.xW0 = slot0; rp.xW1 = nullptr; rp.Whh0 = Wh_d0; rp.Whh1 = nullptr;
    rp.h0 = h0d;
    rp.seq0 = o0; rp.seq1 = nullptr; rp.seq_stride = 512; rp.coloff0 = 0; rp.coloff1 = 0;
    rp.rev0 = 0; rp.rev1 = 0;
    rp.hfin0 = nullptr; rp.hfin1 = nullptr; rp.hfin_stride = 0;
    rp.hbuf = hbuf; rp.bar = bar; rp.spread2 = 1;
    k_lstm_rec<<<128, 256, 0, stream>>>(rp);
  }
  // decoder layer 1
  k_gemm_bt<<<dim3(128, 16), 256, 0, stream>>>(o0, Wb_d1, d1_b, slot1, nullptr, 16384, 2048, 512, 0);
  {
    RecParams rp{};
    rp.xW0 = slot1; rp.xW1 = nullptr; rp.Whh0 = Wh_d1; rp.Whh1 = nullptr;
    rp.h0 = h0d;
    rp.seq0 = o1; rp.seq1 = nullptr; rp.seq_stride = 512; rp.coloff0 = 0; rp.coloff1 = 0;
    rp.rev0 = 0; rp.rev1 = 0;
    rp.hfin0 = nullptr; rp.hfin1 = nullptr; rp.hfin_stride = 0;
    rp.hbuf = hbuf; rp.bar = bar; rp.spread2 = 1;
    k_lstm_rec<<<128, 256, 0, stream>>>(rp);
  }
  // output projection + sigmoid
  k_gemm_bt<<<dim3(128, 1), 256, 0, stream>>>(o1, Wb_out, out_b, nullptr, (float*)d_out, 16384, 128, 512, 1);
}

// Round 3
// 8937.514 us; speedup vs baseline: 1.6812x; 1.1622x over previous
//
#include <hip/hip_runtime.h>
#include <stdint.h>

// LSTM autoencoder: B=64, T=256, P=128, H=512, LAT=128
// out = [x_hat (64*256*128 f32), z (64*128 f32)]

typedef unsigned short u16;
typedef unsigned int u32;
typedef float f32x4 __attribute__((ext_vector_type(4)));
typedef __bf16 bf16x8 __attribute__((ext_vector_type(8)));
typedef unsigned int u32x4 __attribute__((ext_vector_type(4)));

#define AT_LD(p) __hip_atomic_load((p), __ATOMIC_RELAXED, __HIP_MEMORY_SCOPE_AGENT)
#define AT_ST(p, v) __hip_atomic_store((p), (v), __ATOMIC_RELAXED, __HIP_MEMORY_SCOPE_AGENT)

__device__ __forceinline__ u16 f2bf(float f) {
  u32 u = __builtin_bit_cast(u32, f);
  u += 0x7FFFu + ((u >> 16) & 1u);
  return (u16)(u >> 16);
}
__device__ __forceinline__ float bf2f(u16 h) {
  return __builtin_bit_cast(float, (u32)h << 16);
}
__device__ __forceinline__ bf16x8 ld8(const u16* p) {
  u32x4 v = *(const u32x4*)p;
  return __builtin_bit_cast(bf16x8, v);
}
__device__ __forceinline__ float sigf(float x) { return 1.f / (1.f + __expf(-x)); }
__device__ __forceinline__ float tanhx(float x) {
  x = fminf(fmaxf(x, -15.f), 15.f);
  float e = __expf(2.f * x);
  return (e - 1.f) / (e + 1.f);
}

// ---- small prep kernels ----
__global__ void k_prep_x(const float* __restrict__ x, const float* __restrict__ st,
                         u16* __restrict__ Ax, u16* __restrict__ Axs, int n) {
  int i = blockIdx.x * 256 + threadIdx.x;
  if (i >= n) return;
  Ax[i] = f2bf(x[i]);
  int col = i & 127;
  int t = (i >> 7) & 255;
  float v = (t == 0) ? st[col] : x[i - 128];
  Axs[i] = f2bf(v);
}

__global__ void k_cvt(const float* __restrict__ in, u16* __restrict__ out, int n) {
  int i = blockIdx.x * 256 + threadIdx.x;
  if (i < n) out[i] = f2bf(in[i]);
}

// ---- bulk GEMM: C[M][N] = A[M][K] @ B'[N][K]^T + bias, bf16 in, fp32 acc ----
__global__ __launch_bounds__(256) void k_gemm_bt(
    const u16* __restrict__ A, const u16* __restrict__ B, const float* __restrict__ bias,
    u16* __restrict__ Cb, float* __restrict__ Cf, int M, int N, int K, int sig) {
  __shared__ __align__(16) u16 As[128 * 64];
  __shared__ __align__(16) u16 Bs[128 * 64];
  const int m0 = blockIdx.x * 128, n0 = blockIdx.y * 128;
  const int tid = threadIdx.x, lane = tid & 63, wave = tid >> 6;
  const int wm = wave >> 1, wn = wave & 1;

  f32x4 acc[4][4];
#pragma unroll
  for (int i = 0; i < 4; ++i)
#pragma unroll
    for (int j = 0; j < 4; ++j) acc[i][j] = (f32x4){0.f, 0.f, 0.f, 0.f};

  const int nkt = K >> 6;
  for (int kt = 0; kt < nkt; ++kt) {
#pragma unroll
    for (int i = 0; i < 4; ++i) {
      int ch = tid + (i << 8);
      int row = ch >> 3, k8 = ch & 7;
      int dst = row * 128 + ((k8 * 16) ^ ((row & 7) << 4));
      u32x4 va = *(const u32x4*)(A + (size_t)(m0 + row) * K + kt * 64 + k8 * 8);
      *(u32x4*)((char*)As + dst) = va;
      u32x4 vb = *(const u32x4*)(B + (size_t)(n0 + row) * K + kt * 64 + k8 * 8);
      *(u32x4*)((char*)Bs + dst) = vb;
    }
    __syncthreads();
#pragma unroll
    for (int kk = 0; kk < 2; ++kk) {
      int kb = kk * 64 + ((lane >> 4) << 4);
      bf16x8 afr[4], bfr[4];
#pragma unroll
      for (int i = 0; i < 4; ++i) {
        int ra = wm * 64 + i * 16 + (lane & 15);
        afr[i] = ld8((const u16*)((const char*)As + ra * 128 + (kb ^ ((ra & 7) << 4))));
        int rb = wn * 64 + i * 16 + (lane & 15);
        bfr[i] = ld8((const u16*)((const char*)Bs + rb * 128 + (kb ^ ((rb & 7) << 4))));
      }
#pragma unroll
      for (int i = 0; i < 4; ++i)
#pragma unroll
        for (int j = 0; j < 4; ++j)
          acc[i][j] = __builtin_amdgcn_mfma_f32_16x16x32_bf16(afr[i], bfr[j], acc[i][j], 0, 0, 0);
    }
    __syncthreads();
  }
#pragma unroll
  for (int i = 0; i < 4; ++i) {
#pragma unroll
    for (int j = 0; j < 4; ++j) {
      int col = n0 + wn * 64 + j * 16 + (lane & 15);
      float bv = bias ? bias[col] : 0.f;
#pragma unroll
      for (int r = 0; r < 4; ++r) {
        int row = m0 + wm * 64 + i * 16 + ((lane >> 4) << 2) + r;
        float v = acc[i][j][r] + bv;
        if (sig) Cf[(size_t)row * N + col] = 1.f / (1.f + __expf(-v));
        else     Cb[(size_t)row * N + col] = f2bf(v);
      }
    }
  }
}

// ---- persistent recurrent LSTM kernel, tag-broadcast exchange ----
// 8 chains x 32 col-blocks (16 h-cols each). chain = bid&7, c = bid>>3.
// Whh slice (64KB) + optional Wih slice (64KB, fused decoder layer 1) in LDS.
// h exchanged via sc1 atomics in per-writer 512B slices; per-writer monotonic
// tags; single lane-parallel poll replaces the counter barrier.
struct Rec2 {
  const u16* xW[8];      // precomputed x-projection (includes bias); null if fused
  const u16* Whh[8];     // bf16 [2048][512]
  const u16* Wih[8];     // bf16 [2048][512], fused only
  const float* bias[8];  // fused only
  const float* h0[8];    // fp32 [64][512] or null
  u16* seq[8];           // bf16 seq out or null
  float* hfin[8];
  u16* hxc[8];           // exchange base per chain
  int prod[8];           // producer chain (fused)
  int seqstride[8]; int coloff[8]; int rev[8]; int hfinstride[8];
  int grp[8]; int fused[8]; int fullp[8];
  u32* tags;             // [chain][64] u32
};

__global__ __launch_bounds__(256, 1) void k_rec2(Rec2 p) {
  const int chain = blockIdx.x & 7;
  const int c = blockIdx.x >> 3;  // 0..31
  const int tid = threadIdx.x, lane = tid & 63, wave = tid >> 6;  // wave = gate
  const int arow = lane & 15, kg = lane >> 4;

  const u16* __restrict__ xW = p.xW[chain];
  const u16* __restrict__ Whh = p.Whh[chain];
  const u16* __restrict__ Wih = p.Wih[chain];
  const float* __restrict__ bias = p.bias[chain];
  const float* __restrict__ h0 = p.h0[chain];
  u16* seq = p.seq[chain];
  float* hfin = p.hfin[chain];
  u32* hx = (u32*)p.hxc[chain];
  const u32* hxp = (const u32*)p.hxc[p.prod[chain]];
  const int grp = p.grp[chain], rev = p.rev[chain];
  const int fused = p.fused[chain], fullp = p.fullp[chain];
  const int sstride = p.seqstride[chain], coloff = p.coloff[chain];
  const int hstride = p.hfinstride[chain];
  u32* myt = p.tags + chain * 64;
  const u32* pt = p.tags + p.prod[chain] * 64;

  __shared__ __align__(16) u16 Wlds[64][64][8];  // [k>>3][n][k&7], n=gate*16+col
  __shared__ __align__(16) u16 Xlds[64][64][8];
  __shared__ float gbuf[4][16][16];
  __shared__ float cbuf[256];
  __shared__ float bbuf[64];

  // LDS fills: 64 local n-cols (4 gates x 16 cols), full K=512
  for (int e = tid; e < 4096; e += 256) {
    int n = e >> 6, k8 = e & 63;
    int grow = ((n >> 4) << 9) + (c << 4) + (n & 15);
    *(u32x4*)(&Wlds[k8][n][0]) = *(const u32x4*)(Whh + (size_t)grow * 512 + k8 * 8);
    if (fused)
      *(u32x4*)(&Xlds[k8][n][0]) = *(const u32x4*)(Wih + (size_t)grow * 512 + k8 * 8);
  }
  if (tid < 64) bbuf[tid] = fused ? bias[((tid >> 4) << 9) + (c << 4) + (tid & 15)] : 0.f;
  cbuf[tid] = 0.f;
  // publish h_0 slice (slot 0)
  if (tid < 128) {
    int row = tid >> 3, q = tid & 7;
    float a = 0.f, b2 = 0.f;
    if (h0) {
      a = h0[(size_t)(grp * 16 + row) * 512 + (c << 4) + 2 * q];
      b2 = h0[(size_t)(grp * 16 + row) * 512 + (c << 4) + 2 * q + 1];
    }
    u32 pk = (u32)f2bf(a) | ((u32)f2bf(b2) << 16);
    AT_ST(hx + (size_t)c * 128 + (row << 3) + q, pk);
  }
  asm volatile("s_waitcnt vmcnt(0)" ::: "memory");
  __syncthreads();
  if (tid == 0) AT_ST(myt + c, 1u);

  for (int t = 0; t < 256; ++t) {
    const int t_eff = rev ? 255 - t : t;
    const int slot = fullp ? t : (t & 3);
    const int slotn = fullp ? (t + 1) : ((t + 1) & 3);

    // prefetch xW (plain loads; overlap with the poll wait)
    float xwv[4] = {0.f, 0.f, 0.f, 0.f};
    if (!fused) {
#pragma unroll
      for (int r4 = 0; r4 < 4; ++r4) {
        int row = (kg << 2) + r4;
        xwv[r4] = bf2f(xW[(((size_t)((grp * 16 + row) * 256 + t_eff)) << 11) +
                          (wave << 9) + (c << 4) + arow]);
      }
    }
    // poll: own chain tags >= t+1 (skip self); producer tags >= t+2
    {
      u32 thr_own = (u32)(t + 1), thr_prod = (u32)(t + 2);
      while (true) {
        int ok = 1;
        if (lane < 32) {
          if (lane != c) ok = (AT_LD(myt + lane) >= thr_own);
        } else if (fused) {
          ok = (AT_LD(pt + (lane - 32)) >= thr_prod);
        }
        if (__all(ok)) break;
      }
    }
    asm volatile("" ::: "memory");
    __builtin_amdgcn_sched_barrier(0);

    // load A fragments: own h_t (+ producer h_{t+1} if fused)
    bf16x8 af[16], xf[16];
#pragma unroll
    for (int kt = 0; kt < 16; ++kt) {
      const u32* hp = hx + ((size_t)slot * 32 + 2 * kt + (kg >> 1)) * 128 +
                      (arow << 3) + ((kg & 1) << 2);
      u32x4 v;
      v.x = AT_LD(hp + 0); v.y = AT_LD(hp + 1);
      v.z = AT_LD(hp + 2); v.w = AT_LD(hp + 3);
      af[kt] = __builtin_bit_cast(bf16x8, v);
    }
    if (fused) {
#pragma unroll
      for (int kt = 0; kt < 16; ++kt) {
        const u32* hp = hxp + ((size_t)(t + 1) * 32 + 2 * kt + (kg >> 1)) * 128 +
                        (arow << 3) + ((kg & 1) << 2);
        u32x4 v;
        v.x = AT_LD(hp + 0); v.y = AT_LD(hp + 1);
        v.z = AT_LD(hp + 2); v.w = AT_LD(hp + 3);
        xf[kt] = __builtin_bit_cast(bf16x8, v);
      }
    }
    // MFMA: 16 (+16 fused) into split accumulators
    f32x4 ae = {0.f, 0.f, 0.f, 0.f}, ao = {0.f, 0.f, 0.f, 0.f};
#pragma unroll
    for (int kt = 0; kt < 16; ++kt) {
      bf16x8 bw = ld8(&Wlds[(kt << 2) + kg][(wave << 4) + arow][0]);
      if (kt & 1) ao = __builtin_amdgcn_mfma_f32_16x16x32_bf16(af[kt], bw, ao, 0, 0, 0);
      else        ae = __builtin_amdgcn_mfma_f32_16x16x32_bf16(af[kt], bw, ae, 0, 0, 0);
      if (fused) {
        bf16x8 bx = ld8(&Xlds[(kt << 2) + kg][(wave << 4) + arow][0]);
        if (kt & 1) ae = __builtin_amdgcn_mfma_f32_16x16x32_bf16(xf[kt], bx, ae, 0, 0, 0);
        else        ao = __builtin_amdgcn_mfma_f32_16x16x32_bf16(xf[kt], bx, ao, 0, 0, 0);
      }
    }
#pragma unroll
    for (int r4 = 0; r4 < 4; ++r4)
      gbuf[wave][(kg << 2) + r4][arow] = ae[r4] + ao[r4] + xwv[r4];
    __syncthreads();
    // gate math + publish h slice
    if (tid < 128) {
      int row = tid >> 3, q = tid & 7, j0 = q << 1;
      float i0 = gbuf[0][row][j0], i1 = gbuf[0][row][j0 + 1];
      float f0 = gbuf[1][row][j0], f1 = gbuf[1][row][j0 + 1];
      float g0 = gbuf[2][row][j0], g1 = gbuf[2][row][j0 + 1];
      float o0v = gbuf[3][row][j0], o1v = gbuf[3][row][j0 + 1];
      if (fused) {
        i0 += bbuf[j0]; i1 += bbuf[j0 + 1];
        f0 += bbuf[16 + j0]; f1 += bbuf[16 + j0 + 1];
        g0 += bbuf[32 + j0]; g1 += bbuf[32 + j0 + 1];
        o0v += bbuf[48 + j0]; o1v += bbuf[48 + j0 + 1];
      }
      int ci = (row << 4) + j0;
      float cc0 = sigf(f0) * cbuf[ci] + sigf(i0) * tanhx(g0);
      float cc1 = sigf(f1) * cbuf[ci + 1] + sigf(i1) * tanhx(g1);
      cbuf[ci] = cc0; cbuf[ci + 1] = cc1;
      float hh0 = sigf(o0v) * tanhx(cc0);
      float hh1 = sigf(o1v) * tanhx(cc1);
      u32 pk = (u32)f2bf(hh0) | ((u32)f2bf(hh1) << 16);
      AT_ST(hx + ((size_t)slotn * 32 + c) * 128 + (row << 3) + q, pk);
      if (seq)
        *(u32*)(seq + ((size_t)((grp * 16 + row) * 256 + t_eff)) * sstride +
                coloff + (c << 4) + j0) = pk;
      if (hfin && t == 255) {
        hfin[(size_t)(grp * 16 + row) * hstride + (c << 4) + j0] = hh0;
        hfin[(size_t)(grp * 16 + row) * hstride + (c << 4) + j0 + 1] = hh1;
      }
    }
    asm volatile("s_waitcnt vmcnt(0)" ::: "memory");
    __syncthreads();
    if (tid == 0) AT_ST(myt + c, (u32)(t + 2));
  }
}

// ---- tiny heads ----
__global__ void k_enc_head(const float* __restrict__ hcat, const float* __restrict__ W,
                           const float* __restrict__ b, float* __restrict__ zws,
                           float* __restrict__ zout) {
  int bi = blockIdx.x, j = threadIdx.x;
  const float* h = hcat + bi * 1024;
  const float* w = W + j * 1024;
  float s = b[j];
  for (int k = 0; k < 1024; ++k) s += h[k] * w[k];
  zws[bi * 128 + j] = s;
  zout[bi * 128 + j] = s;
}

__global__ void k_dec_head(const float* __restrict__ z, const float* __restrict__ W,
                           const float* __restrict__ b, float* __restrict__ h0d) {
  int bi = blockIdx.x, j = threadIdx.x;
  const float* zz = z + bi * 128;
  const float* w = W + j * 128;
  float s = b[j];
  for (int k = 0; k < 128; ++k) s += zz[k] * w[k];
  h0d[bi * 512 + j] = s;
}

extern "C" void kernel_launch(void* const* d_in, const int* in_sizes, int n_in,
                              void* d_out, int out_size, void* d_ws, size_t ws_size,
                              hipStream_t stream) {
  (void)in_sizes; (void)n_in; (void)out_size;
  const float* x        = (const float*)d_in[0];
  const float* e0f_Wih  = (const float*)d_in[1];
  const float* e0f_Whh  = (const float*)d_in[2];
  const float* e0f_b    = (const float*)d_in[3];
  const float* e0b_Wih  = (const float*)d_in[4];
  const float* e0b_Whh  = (const float*)d_in[5];
  const float* e0b_b    = (const float*)d_in[6];
  const float* e1f_Wih  = (const float*)d_in[7];
  const float* e1f_Whh  = (const float*)d_in[8];
  const float* e1f_b    = (const float*)d_in[9];
  const float* e1b_Wih  = (const float*)d_in[10];
  const float* e1b_Whh  = (const float*)d_in[11];
  const float* e1b_b    = (const float*)d_in[12];
  const float* enc_fc_W = (const float*)d_in[13];
  const float* enc_fc_b = (const float*)d_in[14];
  const float* dec_fc_W = (const float*)d_in[15];
  const float* dec_fc_b = (const float*)d_in[16];
  const float* start_tk = (const float*)d_in[17];
  const float* d0_Wih   = (const float*)d_in[18];
  const float* d0_Whh   = (const float*)d_in[19];
  const float* d0_b     = (const float*)d_in[20];
  const float* d1_Wih   = (const float*)d_in[21];
  const float* d1_Whh   = (const float*)d_in[22];
  const float* d1_b     = (const float*)d_in[23];
  const float* out_W    = (const float*)d_in[24];
  const float* out_b    = (const float*)d_in[25];

  uintptr_t base = (uintptr_t)d_ws;
  size_t off = 0;
  auto carve = [&](size_t bytes) -> void* {
    off = (off + 255) & ~(size_t)255;
    void* p = (void*)(base + off);
    off += bytes;
    return p;
  };
  u16* Ax     = (u16*)carve((size_t)2097152 * 2);
  u16* Axs    = (u16*)carve((size_t)2097152 * 2);
  u16* Wb_e0f = (u16*)carve((size_t)262144 * 2);
  u16* Wb_e0b = (u16*)carve((size_t)262144 * 2);
  u16* Wb_d0  = (u16*)carve((size_t)262144 * 2);
  u16* Wb_e1f = (u16*)carve((size_t)2097152 * 2);
  u16* Wb_e1b = (u16*)carve((size_t)2097152 * 2);
  u16* Wb_d1  = (u16*)carve((size_t)1048576 * 2);
  u16* Wb_out = (u16*)carve((size_t)65536 * 2);
  u16* Wh_e0f = (u16*)carve((size_t)1048576 * 2);
  u16* Wh_e0b = (u16*)carve((size_t)1048576 * 2);
  u16* Wh_e1f = (u16*)carve((size_t)1048576 * 2);
  u16* Wh_e1b = (u16*)carve((size_t)1048576 * 2);
  u16* Wh_d0  = (u16*)carve((size_t)1048576 * 2);
  u16* Wh_d1  = (u16*)carve((size_t)1048576 * 2);
  u16* slot0  = (u16*)carve((size_t)16384 * 2048 * 2);
  u16* slot1  = (u16*)carve((size_t)16384 * 2048 * 2);
  u16* l0     = (u16*)carve((size_t)33619968);  // l0 (32MB); later o1 + hxprod
  u16* hxring = (u16*)carve((size_t)524288);    // 8 chains x 4 slots x 32 w x 512B
  float* hcat = (float*)carve((size_t)65536 * 4);
  float* zws  = (float*)carve((size_t)8192 * 4);
  float* h0d  = (float*)carve((size_t)32768 * 4);
  u32* tags0  = (u32*)carve(2048);
  u32* tags1  = (u32*)carve(2048);
  u32* tags2  = (u32*)carve(2048);
  if (off > ws_size) return;

  u16* o1     = l0;                // alias: l0 dead after e1 gemms
  u16* hxprod = l0 + 8388608;      // +16MiB (u16 units)

  (void)hipMemsetAsync(tags0, 0, 6144, stream);

  k_prep_x<<<8192, 256, 0, stream>>>(x, start_tk, Ax, Axs, 2097152);
  k_cvt<<<1024, 256, 0, stream>>>(e0f_Wih, Wb_e0f, 262144);
  k_cvt<<<1024, 256, 0, stream>>>(e0b_Wih, Wb_e0b, 262144);
  k_cvt<<<1024, 256, 0, stream>>>(d0_Wih, Wb_d0, 262144);
  k_cvt<<<8192, 256, 0, stream>>>(e1f_Wih, Wb_e1f, 2097152);
  k_cvt<<<8192, 256, 0, stream>>>(e1b_Wih, Wb_e1b, 2097152);
  k_cvt<<<4096, 256, 0, stream>>>(d1_Wih, Wb_d1, 1048576);
  k_cvt<<<256, 256, 0, stream>>>(out_W, Wb_out, 65536);
  k_cvt<<<4096, 256, 0, stream>>>(e0f_Whh, Wh_e0f, 1048576);
  k_cvt<<<4096, 256, 0, stream>>>(e0b_Whh, Wh_e0b, 1048576);
  k_cvt<<<4096, 256, 0, stream>>>(e1f_Whh, Wh_e1f, 1048576);
  k_cvt<<<4096, 256, 0, stream>>>(e1b_Whh, Wh_e1b, 1048576);
  k_cvt<<<4096, 256, 0, stream>>>(d0_Whh, Wh_d0, 1048576);
  k_cvt<<<4096, 256, 0, stream>>>(d1_Whh, Wh_d1, 1048576);

  // encoder layer 0 projections + recurrence -> l0
  k_gemm_bt<<<dim3(128, 16), 256, 0, stream>>>(Ax, Wb_e0f, e0f_b, slot0, nullptr, 16384, 2048, 128, 0);
  k_gemm_bt<<<dim3(128, 16), 256, 0, stream>>>(Ax, Wb_e0b, e0b_b, slot1, nullptr, 16384, 2048, 128, 0);
  {
    Rec2 r{};
    for (int ch = 0; ch < 8; ++ch) {
      int dir2 = ch >> 2, g = ch & 3;
      r.xW[ch] = dir2 ? slot1 : slot0;
      r.Whh[ch] = dir2 ? Wh_e0b : Wh_e0f;
      r.Wih[ch] = nullptr; r.bias[ch] = nullptr; r.h0[ch] = nullptr;
      r.seq[ch] = l0; r.seqstride[ch] = 1024; r.coloff[ch] = dir2 ? 512 : 0;
      r.rev[ch] = dir2; r.hfin[ch] = nullptr; r.hfinstride[ch] = 0;
      r.grp[ch] = g; r.fused[ch] = 0; r.fullp[ch] = 0; r.prod[ch] = 0;
      r.hxc[ch] = hxring + (size_t)ch * 32768;
    }
    r.tags = tags0;
    k_rec2<<<256, 256, 0, stream>>>(r);
  }
  // encoder layer 1 projections + recurrence -> hcat
  k_gemm_bt<<<dim3(128, 16), 256, 0, stream>>>(l0, Wb_e1f, e1f_b, slot0, nullptr, 16384, 2048, 1024, 0);
  k_gemm_bt<<<dim3(128, 16), 256, 0, stream>>>(l0, Wb_e1b, e1b_b, slot1, nullptr, 16384, 2048, 1024, 0);
  {
    Rec2 r{};
    for (int ch = 0; ch < 8; ++ch) {
      int dir2 = ch >> 2, g = ch & 3;
      r.xW[ch] = dir2 ? slot1 : slot0;
      r.Whh[ch] = dir2 ? Wh_e1b : Wh_e1f;
      r.Wih[ch] = nullptr; r.bias[ch] = nullptr; r.h0[ch] = nullptr;
      r.seq[ch] = nullptr; r.seqstride[ch] = 0; r.coloff[ch] = 0;
      r.rev[ch] = dir2; r.hfin[ch] = hcat + (dir2 ? 512 : 0); r.hfinstride[ch] = 1024;
      r.grp[ch] = g; r.fused[ch] = 0; r.fullp[ch] = 0; r.prod[ch] = 0;
      r.hxc[ch] = hxring + (size_t)ch * 32768;
    }
    r.tags = tags1;
    k_rec2<<<256, 256, 0, stream>>>(r);
  }
  // bottleneck
  k_enc_head<<<64, 128, 0, stream>>>(hcat, enc_fc_W, enc_fc_b, zws, ((float*)d_out) + 2097152);
  k_dec_head<<<64, 512, 0, stream>>>(zws, dec_fc_W, dec_fc_b, h0d);
  // decoder: d0 projection, then fused d0||d1 recurrence -> o1
  k_gemm_bt<<<dim3(128, 16), 256, 0, stream>>>(Axs, Wb_d0, d0_b, slot0, nullptr, 16384, 2048, 128, 0);
  {
    Rec2 r{};
    for (int ch = 0; ch < 4; ++ch) {  // d0 chains: full-depth producers
      r.xW[ch] = slot0;
      r.Whh[ch] = Wh_d0;
      r.Wih[ch] = nullptr; r.bias[ch] = nullptr; r.h0[ch] = h0d;
      r.seq[ch] = nullptr; r.seqstride[ch] = 0; r.coloff[ch] = 0;
      r.rev[ch] = 0; r.hfin[ch] = nullptr; r.hfinstride[ch] = 0;
      r.grp[ch] = ch; r.fused[ch] = 0; r.fullp[ch] = 1; r.prod[ch] = 0;
      r.hxc[ch] = hxprod + (size_t)ch * 2105344;  // 257*32*256 u16
    }
    for (int ch = 4; ch < 8; ++ch) {  // d1 chains: fused consumers (own xW GEMM)
      r.xW[ch] = nullptr;
      r.Whh[ch] = Wh_d1;
      r.Wih[ch] = Wb_d1; r.bias[ch] = d1_b; r.h0[ch] = h0d;
      r.seq[ch] = o1; r.seqstride[ch] = 512; r.coloff[ch] = 0;
      r.rev[ch] = 0; r.hfin[ch] = nullptr; r.hfinstride[ch] = 0;
      r.grp[ch] = ch - 4; r.fused[ch] = 1; r.fullp[ch] = 0; r.prod[ch] = ch - 4;
      r.hxc[ch] = hxring + (size_t)ch * 32768;
    }
    r.tags = tags2;
    k_rec2<<<256, 256, 0, stream>>>(r);
  }
  // output projection + sigmoid
  k_gemm_bt<<<dim3(128, 1), 256, 0, stream>>>(o1, Wb_out, out_b, nullptr, (float*)d_out, 16384, 128, 512, 1);
}

// Round 4
// 5517.543 us; speedup vs baseline: 2.7233x; 1.6198x over previous
//
#include <hip/hip_runtime.h>
#include <stdint.h>

// LSTM autoencoder: B=64, T=256, P=128, H=512, LAT=128
// out = [x_hat (64*256*128 f32), z (64*128 f32)]

typedef unsigned short u16;
typedef unsigned int u32;
typedef float f32x4 __attribute__((ext_vector_type(4)));
typedef __bf16 bf16x8 __attribute__((ext_vector_type(8)));
typedef unsigned int u32x4 __attribute__((ext_vector_type(4)));

#define AT_LD(p) __hip_atomic_load((p), __ATOMIC_RELAXED, __HIP_MEMORY_SCOPE_AGENT)
#define AT_ST(p, v) __hip_atomic_store((p), (v), __ATOMIC_RELAXED, __HIP_MEMORY_SCOPE_AGENT)

__device__ __forceinline__ u16 f2bf(float f) {
  u32 u = __builtin_bit_cast(u32, f);
  u += 0x7FFFu + ((u >> 16) & 1u);
  return (u16)(u >> 16);
}
__device__ __forceinline__ float bf2f(u16 h) {
  return __builtin_bit_cast(float, (u32)h << 16);
}
__device__ __forceinline__ bf16x8 ld8(const u16* p) {
  u32x4 v = *(const u32x4*)p;
  return __builtin_bit_cast(bf16x8, v);
}
__device__ __forceinline__ float sigf(float x) { return 1.f / (1.f + __expf(-x)); }
__device__ __forceinline__ float tanhx(float x) {
  x = fminf(fmaxf(x, -15.f), 15.f);
  float e = __expf(2.f * x);
  return (e - 1.f) / (e + 1.f);
}

// ---- small prep kernels ----
__global__ void k_prep_x(const float* __restrict__ x, const float* __restrict__ st,
                         u16* __restrict__ Ax, u16* __restrict__ Axs, int n) {
  int i = blockIdx.x * 256 + threadIdx.x;
  if (i >= n) return;
  Ax[i] = f2bf(x[i]);
  int col = i & 127;
  int t = (i >> 7) & 255;
  float v = (t == 0) ? st[col] : x[i - 128];
  Axs[i] = f2bf(v);
}

__global__ void k_cvt(const float* __restrict__ in, u16* __restrict__ out, int n) {
  int i = blockIdx.x * 256 + threadIdx.x;
  if (i < n) out[i] = f2bf(in[i]);
}

// ---- bulk GEMM: C[M][N] = A[M][K] @ B'[N][K]^T + bias, bf16 in, fp32 acc ----
__global__ __launch_bounds__(256) void k_gemm_bt(
    const u16* __restrict__ A, const u16* __restrict__ B, const float* __restrict__ bias,
    u16* __restrict__ Cb, float* __restrict__ Cf, int M, int N, int K, int sig) {
  __shared__ __align__(16) u16 As[128 * 64];
  __shared__ __align__(16) u16 Bs[128 * 64];
  const int m0 = blockIdx.x * 128, n0 = blockIdx.y * 128;
  const int tid = threadIdx.x, lane = tid & 63, wave = tid >> 6;
  const int wm = wave >> 1, wn = wave & 1;

  f32x4 acc[4][4];
#pragma unroll
  for (int i = 0; i < 4; ++i)
#pragma unroll
    for (int j = 0; j < 4; ++j) acc[i][j] = (f32x4){0.f, 0.f, 0.f, 0.f};

  const int nkt = K >> 6;
  for (int kt = 0; kt < nkt; ++kt) {
#pragma unroll
    for (int i = 0; i < 4; ++i) {
      int ch = tid + (i << 8);
      int row = ch >> 3, k8 = ch & 7;
      int dst = row * 128 + ((k8 * 16) ^ ((row & 7) << 4));
      u32x4 va = *(const u32x4*)(A + (size_t)(m0 + row) * K + kt * 64 + k8 * 8);
      *(u32x4*)((char*)As + dst) = va;
      u32x4 vb = *(const u32x4*)(B + (size_t)(n0 + row) * K + kt * 64 + k8 * 8);
      *(u32x4*)((char*)Bs + dst) = vb;
    }
    __syncthreads();
#pragma unroll
    for (int kk = 0; kk < 2; ++kk) {
      int kb = kk * 64 + ((lane >> 4) << 4);
      bf16x8 afr[4], bfr[4];
#pragma unroll
      for (int i = 0; i < 4; ++i) {
        int ra = wm * 64 + i * 16 + (lane & 15);
        afr[i] = ld8((const u16*)((const char*)As + ra * 128 + (kb ^ ((ra & 7) << 4))));
        int rb = wn * 64 + i * 16 + (lane & 15);
        bfr[i] = ld8((const u16*)((const char*)Bs + rb * 128 + (kb ^ ((rb & 7) << 4))));
      }
#pragma unroll
      for (int i = 0; i < 4; ++i)
#pragma unroll
        for (int j = 0; j < 4; ++j)
          acc[i][j] = __builtin_amdgcn_mfma_f32_16x16x32_bf16(afr[i], bfr[j], acc[i][j], 0, 0, 0);
    }
    __syncthreads();
  }
#pragma unroll
  for (int i = 0; i < 4; ++i) {
#pragma unroll
    for (int j = 0; j < 4; ++j) {
      int col = n0 + wn * 64 + j * 16 + (lane & 15);
      float bv = bias ? bias[col] : 0.f;
#pragma unroll
      for (int r = 0; r < 4; ++r) {
        int row = m0 + wm * 64 + i * 16 + ((lane >> 4) << 2) + r;
        float v = acc[i][j][r] + bv;
        if (sig) Cf[(size_t)row * N + col] = 1.f / (1.f + __expf(-v));
        else     Cb[(size_t)row * N + col] = f2bf(v);
      }
    }
  }
}

// ---- persistent recurrent LSTM kernel, tag-broadcast exchange ----
// 8 chains x 32 col-blocks (16 h-cols each). chain = bid&7, c = bid>>3.
// Poll discipline: ONLY wave 0 polls (s_sleep backoff); others held at barrier.
// Own-chain h staged into LDS once per step (swizzled); A-fragments via
// ds_read_b128. Gate math / h publish / tag by waves 2-3; seq stores after tag.
struct Rec2 {
  const u16* xW[8];      // precomputed x-projection (includes bias); null if fused
  const u16* Whh[8];     // bf16 [2048][512]
  const u16* Wih[8];     // bf16 [2048][512], fused only
  const float* bias[8];  // fused only
  const float* h0[8];    // fp32 [64][512] or null
  u16* seq[8];           // bf16 seq out or null
  float* hfin[8];
  u16* hxc[8];           // exchange base per chain
  int prod[8];           // producer chain (fused)
  int seqstride[8]; int coloff[8]; int rev[8]; int hfinstride[8];
  int grp[8]; int fused[8]; int fullp[8];
  u32* tags;             // [chain][64] u32
};

__global__ __launch_bounds__(256, 1) void k_rec2(Rec2 p) {
  const int chain = blockIdx.x & 7;
  const int c = blockIdx.x >> 3;  // 0..31
  const int tid = threadIdx.x, lane = tid & 63, wave = tid >> 6;  // wave = gate
  const int arow = lane & 15, kg = lane >> 4;

  const u16* __restrict__ xW = p.xW[chain];
  const u16* __restrict__ Whh = p.Whh[chain];
  const u16* __restrict__ Wih = p.Wih[chain];
  const float* __restrict__ bias = p.bias[chain];
  const float* __restrict__ h0 = p.h0[chain];
  u16* seq = p.seq[chain];
  float* hfin = p.hfin[chain];
  u32* hx = (u32*)p.hxc[chain];
  const u32* hxp = (const u32*)p.hxc[p.prod[chain]];
  const int grp = p.grp[chain], rev = p.rev[chain];
  const int fused = p.fused[chain], fullp = p.fullp[chain];
  const int sstride = p.seqstride[chain], coloff = p.coloff[chain];
  const int hstride = p.hfinstride[chain];
  u32* myt = p.tags + chain * 64;
  const u32* pt = p.tags + p.prod[chain] * 64;

  __shared__ __align__(16) u16 Wlds[64][64][8];  // [k>>3][n][k&7], n=gate*16+col
  __shared__ __align__(16) u16 Xlds[64][64][8];
  __shared__ __align__(16) u16 hbufA[8192];      // 16 rows x 512 cols, XOR-swizzled
  __shared__ float gbuf[4][16][16];
  __shared__ float cbuf[256];
  __shared__ float bbuf[64];

  // LDS weight fills: 64 local n-cols (4 gates x 16 cols), full K=512
  for (int e = tid; e < 4096; e += 256) {
    int n = e >> 6, k8 = e & 63;
    int grow = ((n >> 4) << 9) + (c << 4) + (n & 15);
    *(u32x4*)(&Wlds[k8][n][0]) = *(const u32x4*)(Whh + (size_t)grow * 512 + k8 * 8);
    if (fused)
      *(u32x4*)(&Xlds[k8][n][0]) = *(const u32x4*)(Wih + (size_t)grow * 512 + k8 * 8);
  }
  if (tid < 64) bbuf[tid] = fused ? bias[((tid >> 4) << 9) + (c << 4) + (tid & 15)] : 0.f;
  cbuf[tid] = 0.f;
  // publish h_0 slice (slot 0)
  if (tid < 128) {
    int row = tid >> 3, q = tid & 7;
    float a = 0.f, b2 = 0.f;
    if (h0) {
      a = h0[(size_t)(grp * 16 + row) * 512 + (c << 4) + 2 * q];
      b2 = h0[(size_t)(grp * 16 + row) * 512 + (c << 4) + 2 * q + 1];
    }
    u32 pk = (u32)f2bf(a) | ((u32)f2bf(b2) << 16);
    AT_ST(hx + (size_t)c * 128 + (row << 3) + q, pk);
  }
  asm volatile("s_waitcnt vmcnt(0)" ::: "memory");
  __syncthreads();
  if (tid == 0) AT_ST(myt + c, 1u);

  for (int t = 0; t < 256; ++t) {
    const int t_eff = rev ? 255 - t : t;
    const int slot = fullp ? t : (t & 3);
    const int slotn = fullp ? (t + 1) : ((t + 1) & 3);

    // xW prefetch at loop top: HBM latency drains under the poll wait
    float xwv[4] = {0.f, 0.f, 0.f, 0.f};
    if (!fused) {
#pragma unroll
      for (int r4 = 0; r4 < 4; ++r4) {
        int row = (kg << 2) + r4;
        xwv[r4] = bf2f(xW[(((size_t)((grp * 16 + row) * 256 + t_eff)) << 11) +
                          (wave << 9) + (c << 4) + arow]);
      }
    }
    // poll: wave 0 only, with backoff. lanes<32: own chain (skip self);
    // lanes>=32: producer chain (fused only).
    if (wave == 0) {
      u32 thr_own = (u32)(t + 1), thr_prod = (u32)(t + 2);
      while (true) {
        int ok = 1;
        if (lane < 32) {
          if (lane != c) ok = (AT_LD(myt + lane) >= thr_own);
        } else if (fused) {
          ok = (AT_LD(pt + (lane - 32)) >= thr_prod);
        }
        if (__all(ok)) break;
        __builtin_amdgcn_s_sleep(1);
      }
    }
    __syncthreads();  // release: peers' h (and producer h) now safe to read
    __builtin_amdgcn_sched_barrier(0);

    // stage own-chain h_t into LDS once (cooperative, swizzled)
#pragma unroll
    for (int i = 0; i < 4; ++i) {
      int cid = tid + (i << 8);          // 0..1023: 16 rows x 64 16B-chunks
      int row = cid >> 6, ch8 = cid & 63;
      const u32* src = hx + ((size_t)slot * 32 + (ch8 >> 1)) * 128 +
                       (row << 3) + ((ch8 & 1) << 2);
      u32x4 v;
      v.x = AT_LD(src + 0); v.y = AT_LD(src + 1);
      v.z = AT_LD(src + 2); v.w = AT_LD(src + 3);
      *(u32x4*)((char*)hbufA + row * 1024 + ((ch8 << 4) ^ ((row & 7) << 4))) = v;
    }
    // fused: producer h_{t+1} fragments direct (regs)
    bf16x8 xf[16];
    if (fused) {
#pragma unroll
      for (int kt = 0; kt < 16; ++kt) {
        const u32* hp = hxp + ((size_t)(t + 1) * 32 + 2 * kt + (kg >> 1)) * 128 +
                        (arow << 3) + ((kg & 1) << 2);
        u32x4 v;
        v.x = AT_LD(hp + 0); v.y = AT_LD(hp + 1);
        v.z = AT_LD(hp + 2); v.w = AT_LD(hp + 3);
        xf[kt] = __builtin_bit_cast(bf16x8, v);
      }
    }
    __syncthreads();  // hbufA visible

    // A-fragments from LDS, MFMA into split accumulators
    bf16x8 af[16];
#pragma unroll
    for (int kt = 0; kt < 16; ++kt)
      af[kt] = ld8((const u16*)((const char*)hbufA + arow * 1024 +
                                ((kt * 64 + (kg << 4)) ^ ((arow & 7) << 4))));
    f32x4 ae = {0.f, 0.f, 0.f, 0.f}, ao = {0.f, 0.f, 0.f, 0.f};
#pragma unroll
    for (int kt = 0; kt < 16; ++kt) {
      bf16x8 bw = ld8(&Wlds[(kt << 2) + kg][(wave << 4) + arow][0]);
      if (kt & 1) ao = __builtin_amdgcn_mfma_f32_16x16x32_bf16(af[kt], bw, ao, 0, 0, 0);
      else        ae = __builtin_amdgcn_mfma_f32_16x16x32_bf16(af[kt], bw, ae, 0, 0, 0);
      if (fused) {
        bf16x8 bx = ld8(&Xlds[(kt << 2) + kg][(wave << 4) + arow][0]);
        if (kt & 1) ae = __builtin_amdgcn_mfma_f32_16x16x32_bf16(xf[kt], bx, ae, 0, 0, 0);
        else        ao = __builtin_amdgcn_mfma_f32_16x16x32_bf16(xf[kt], bx, ao, 0, 0, 0);
      }
    }
#pragma unroll
    for (int r4 = 0; r4 < 4; ++r4)
      gbuf[wave][(kg << 2) + r4][arow] = ae[r4] + ao[r4] + xwv[r4];
    __syncthreads();

    // gate math + h publish: waves 2,3 only (keeps poller/drain paths clean)
    u32 pk = 0; int row2 = 0, j0 = 0;
    float hh0 = 0.f, hh1 = 0.f;
    if (tid >= 128) {
      int t2 = tid - 128;
      row2 = t2 >> 3; int q = t2 & 7; j0 = q << 1;
      float i0 = gbuf[0][row2][j0], i1 = gbuf[0][row2][j0 + 1];
      float f0 = gbuf[1][row2][j0], f1 = gbuf[1][row2][j0 + 1];
      float g0 = gbuf[2][row2][j0], g1 = gbuf[2][row2][j0 + 1];
      float o0v = gbuf[3][row2][j0], o1v = gbuf[3][row2][j0 + 1];
      if (fused) {
        i0 += bbuf[j0]; i1 += bbuf[j0 + 1];
        f0 += bbuf[16 + j0]; f1 += bbuf[16 + j0 + 1];
        g0 += bbuf[32 + j0]; g1 += bbuf[32 + j0 + 1];
        o0v += bbuf[48 + j0]; o1v += bbuf[48 + j0 + 1];
      }
      int ci = (row2 << 4) + j0;
      float cc0 = sigf(f0) * cbuf[ci] + sigf(i0) * tanhx(g0);
      float cc1 = sigf(f1) * cbuf[ci + 1] + sigf(i1) * tanhx(g1);
      cbuf[ci] = cc0; cbuf[ci + 1] = cc1;
      hh0 = sigf(o0v) * tanhx(cc0);
      hh1 = sigf(o1v) * tanhx(cc1);
      pk = (u32)f2bf(hh0) | ((u32)f2bf(hh1) << 16);
      AT_ST(hx + ((size_t)slotn * 32 + c) * 128 + (row2 << 3) + q, pk);
      asm volatile("s_waitcnt vmcnt(0)" ::: "memory");
    }
    __syncthreads();  // h stores drained by waves 2,3 before tag
    if (tid == 128) AT_ST(myt + c, (u32)(t + 2));
    if (tid >= 128) {
      // bulk outputs AFTER the tag: their HBM drain hides under the next poll
      if (seq)
        *(u32*)(seq + ((size_t)((grp * 16 + row2) * 256 + t_eff)) * sstride +
                coloff + (c << 4) + j0) = pk;
      if (hfin && t == 255) {
        hfin[(size_t)(grp * 16 + row2) * hstride + (c << 4) + j0] = hh0;
        hfin[(size_t)(grp * 16 + row2) * hstride + (c << 4) + j0 + 1] = hh1;
      }
    }
  }
}

// ---- tiny heads ----
__global__ void k_enc_head(const float* __restrict__ hcat, const float* __restrict__ W,
                           const float* __restrict__ b, float* __restrict__ zws,
                           float* __restrict__ zout) {
  int bi = blockIdx.x, j = threadIdx.x;
  const float* h = hcat + bi * 1024;
  const float* w = W + j * 1024;
  float s = b[j];
  for (int k = 0; k < 1024; ++k) s += h[k] * w[k];
  zws[bi * 128 + j] = s;
  zout[bi * 128 + j] = s;
}

__global__ void k_dec_head(const float* __restrict__ z, const float* __restrict__ W,
                           const float* __restrict__ b, float* __restrict__ h0d) {
  int bi = blockIdx.x, j = threadIdx.x;
  const float* zz = z + bi * 128;
  const float* w = W + j * 128;
  float s = b[j];
  for (int k = 0; k < 128; ++k) s += zz[k] * w[k];
  h0d[bi * 512 + j] = s;
}

extern "C" void kernel_launch(void* const* d_in, const int* in_sizes, int n_in,
                              void* d_out, int out_size, void* d_ws, size_t ws_size,
                              hipStream_t stream) {
  (void)in_sizes; (void)n_in; (void)out_size;
  const float* x        = (const float*)d_in[0];
  const float* e0f_Wih  = (const float*)d_in[1];
  const float* e0f_Whh  = (const float*)d_in[2];
  const float* e0f_b    = (const float*)d_in[3];
  const float* e0b_Wih  = (const float*)d_in[4];
  const float* e0b_Whh  = (const float*)d_in[5];
  const float* e0b_b    = (const float*)d_in[6];
  const float* e1f_Wih  = (const float*)d_in[7];
  const float* e1f_Whh  = (const float*)d_in[8];
  const float* e1f_b    = (const float*)d_in[9];
  const float* e1b_Wih  = (const float*)d_in[10];
  const float* e1b_Whh  = (const float*)d_in[11];
  const float* e1b_b    = (const float*)d_in[12];
  const float* enc_fc_W = (const float*)d_in[13];
  const float* enc_fc_b = (const float*)d_in[14];
  const float* dec_fc_W = (const float*)d_in[15];
  const float* dec_fc_b = (const float*)d_in[16];
  const float* start_tk = (const float*)d_in[17];
  const float* d0_Wih   = (const float*)d_in[18];
  const float* d0_Whh   = (const float*)d_in[19];
  const float* d0_b     = (const float*)d_in[20];
  const float* d1_Wih   = (const float*)d_in[21];
  const float* d1_Whh   = (const float*)d_in[22];
  const float* d1_b     = (const float*)d_in[23];
  const float* out_W    = (const float*)d_in[24];
  const float* out_b    = (const float*)d_in[25];

  uintptr_t base = (uintptr_t)d_ws;
  size_t off = 0;
  auto carve = [&](size_t bytes) -> void* {
    off = (off + 255) & ~(size_t)255;
    void* p = (void*)(base + off);
    off += bytes;
    return p;
  };
  u16* Ax     = (u16*)carve((size_t)2097152 * 2);
  u16* Axs    = (u16*)carve((size_t)2097152 * 2);
  u16* Wb_e0f = (u16*)carve((size_t)262144 * 2);
  u16* Wb_e0b = (u16*)carve((size_t)262144 * 2);
  u16* Wb_d0  = (u16*)carve((size_t)262144 * 2);
  u16* Wb_e1f = (u16*)carve((size_t)2097152 * 2);
  u16* Wb_e1b = (u16*)carve((size_t)2097152 * 2);
  u16* Wb_d1  = (u16*)carve((size_t)1048576 * 2);
  u16* Wb_out = (u16*)carve((size_t)65536 * 2);
  u16* Wh_e0f = (u16*)carve((size_t)1048576 * 2);
  u16* Wh_e0b = (u16*)carve((size_t)1048576 * 2);
  u16* Wh_e1f = (u16*)carve((size_t)1048576 * 2);
  u16* Wh_e1b = (u16*)carve((size_t)1048576 * 2);
  u16* Wh_d0  = (u16*)carve((size_t)1048576 * 2);
  u16* Wh_d1  = (u16*)carve((size_t)1048576 * 2);
  u16* slot0  = (u16*)carve((size_t)16384 * 2048 * 2);
  u16* slot1  = (u16*)carve((size_t)16384 * 2048 * 2);
  u16* l0     = (u16*)carve((size_t)33619968);  // l0 (32MB); later o1 + hxprod
  u16* hxring = (u16*)carve((size_t)524288);    // 8 chains x 4 slots x 32 w x 512B
  float* hcat = (float*)carve((size_t)65536 * 4);
  float* zws  = (float*)carve((size_t)8192 * 4);
  float* h0d  = (float*)carve((size_t)32768 * 4);
  u32* tags0  = (u32*)carve(2048);
  u32* tags1  = (u32*)carve(2048);
  u32* tags2  = (u32*)carve(2048);
  if (off > ws_size) return;

  u16* o1     = l0;                // alias: l0 dead after e1 gemms
  u16* hxprod = l0 + 8388608;      // +16MiB (u16 units)

  (void)hipMemsetAsync(tags0, 0, 6144, stream);

  k_prep_x<<<8192, 256, 0, stream>>>(x, start_tk, Ax, Axs, 2097152);
  k_cvt<<<1024, 256, 0, stream>>>(e0f_Wih, Wb_e0f, 262144);
  k_cvt<<<1024, 256, 0, stream>>>(e0b_Wih, Wb_e0b, 262144);
  k_cvt<<<1024, 256, 0, stream>>>(d0_Wih, Wb_d0, 262144);
  k_cvt<<<8192, 256, 0, stream>>>(e1f_Wih, Wb_e1f, 2097152);
  k_cvt<<<8192, 256, 0, stream>>>(e1b_Wih, Wb_e1b, 2097152);
  k_cvt<<<4096, 256, 0, stream>>>(d1_Wih, Wb_d1, 1048576);
  k_cvt<<<256, 256, 0, stream>>>(out_W, Wb_out, 65536);
  k_cvt<<<4096, 256, 0, stream>>>(e0f_Whh, Wh_e0f, 1048576);
  k_cvt<<<4096, 256, 0, stream>>>(e0b_Whh, Wh_e0b, 1048576);
  k_cvt<<<4096, 256, 0, stream>>>(e1f_Whh, Wh_e1f, 1048576);
  k_cvt<<<4096, 256, 0, stream>>>(e1b_Whh, Wh_e1b, 1048576);
  k_cvt<<<4096, 256, 0, stream>>>(d0_Whh, Wh_d0, 1048576);
  k_cvt<<<4096, 256, 0, stream>>>(d1_Whh, Wh_d1, 1048576);

  // encoder layer 0 projections + recurrence -> l0
  k_gemm_bt<<<dim3(128, 16), 256, 0, stream>>>(Ax, Wb_e0f, e0f_b, slot0, nullptr, 16384, 2048, 128, 0);
  k_gemm_bt<<<dim3(128, 16), 256, 0, stream>>>(Ax, Wb_e0b, e0b_b, slot1, nullptr, 16384, 2048, 128, 0);
  {
    Rec2 r{};
    for (int ch = 0; ch < 8; ++ch) {
      int dir2 = ch >> 2, g = ch & 3;
      r.xW[ch] = dir2 ? slot1 : slot0;
      r.Whh[ch] = dir2 ? Wh_e0b : Wh_e0f;
      r.Wih[ch] = nullptr; r.bias[ch] = nullptr; r.h0[ch] = nullptr;
      r.seq[ch] = l0; r.seqstride[ch] = 1024; r.coloff[ch] = dir2 ? 512 : 0;
      r.rev[ch] = dir2; r.hfin[ch] = nullptr; r.hfinstride[ch] = 0;
      r.grp[ch] = g; r.fused[ch] = 0; r.fullp[ch] = 0; r.prod[ch] = 0;
      r.hxc[ch] = hxring + (size_t)ch * 32768;
    }
    r.tags = tags0;
    k_rec2<<<256, 256, 0, stream>>>(r);
  }
  // encoder layer 1 projections + recurrence -> hcat
  k_gemm_bt<<<dim3(128, 16), 256, 0, stream>>>(l0, Wb_e1f, e1f_b, slot0, nullptr, 16384, 2048, 1024, 0);
  k_gemm_bt<<<dim3(128, 16), 256, 0, stream>>>(l0, Wb_e1b, e1b_b, slot1, nullptr, 16384, 2048, 1024, 0);
  {
    Rec2 r{};
    for (int ch = 0; ch < 8; ++ch) {
      int dir2 = ch >> 2, g = ch & 3;
      r.xW[ch] = dir2 ? slot1 : slot0;
      r.Whh[ch] = dir2 ? Wh_e1b : Wh_e1f;
      r.Wih[ch] = nullptr; r.bias[ch] = nullptr; r.h0[ch] = nullptr;
      r.seq[ch] = nullptr; r.seqstride[ch] = 0; r.coloff[ch] = 0;
      r.rev[ch] = dir2; r.hfin[ch] = hcat + (dir2 ? 512 : 0); r.hfinstride[ch] = 1024;
      r.grp[ch] = g; r.fused[ch] = 0; r.fullp[ch] = 0; r.prod[ch] = 0;
      r.hxc[ch] = hxring + (size_t)ch * 32768;
    }
    r.tags = tags1;
    k_rec2<<<256, 256, 0, stream>>>(r);
  }
  // bottleneck
  k_enc_head<<<64, 128, 0, stream>>>(hcat, enc_fc_W, enc_fc_b, zws, ((float*)d_out) + 2097152);
  k_dec_head<<<64, 512, 0, stream>>>(zws, dec_fc_W, dec_fc_b, h0d);
  // decoder: d0 projection, then fused d0||d1 recurrence -> o1
  k_gemm_bt<<<dim3(128, 16), 256, 0, stream>>>(Axs, Wb_d0, d0_b, slot0, nullptr, 16384, 2048, 128, 0);
  {
    Rec2 r{};
    for (int ch = 0; ch < 4; ++ch) {  // d0 chains: full-depth producers
      r.xW[ch] = slot0;
      r.Whh[ch] = Wh_d0;
      r.Wih[ch] = nullptr; r.bias[ch] = nullptr; r.h0[ch] = h0d;
      r.seq[ch] = nullptr; r.seqstride[ch] = 0; r.coloff[ch] = 0;
      r.rev[ch] = 0; r.hfin[ch] = nullptr; r.hfinstride[ch] = 0;
      r.grp[ch] = ch; r.fused[ch] = 0; r.fullp[ch] = 1; r.prod[ch] = 0;
      r.hxc[ch] = hxprod + (size_t)ch * 2105344;  // 257*32*256 u16
    }
    for (int ch = 4; ch < 8; ++ch) {  // d1 chains: fused consumers (own xW GEMM)
      r.xW[ch] = nullptr;
      r.Whh[ch] = Wh_d1;
      r.Wih[ch] = Wb_d1; r.bias[ch] = d1_b; r.h0[ch] = h0d;
      r.seq[ch] = o1; r.seqstride[ch] = 512; r.coloff[ch] = 0;
      r.rev[ch] = 0; r.hfin[ch] = nullptr; r.hfinstride[ch] = 0;
      r.grp[ch] = ch - 4; r.fused[ch] = 1; r.fullp[ch] = 0; r.prod[ch] = ch - 4;
      r.hxc[ch] = hxring + (size_t)ch * 32768;
    }
    r.tags = tags2;
    k_rec2<<<256, 256, 0, stream>>>(r);
  }
  // output projection + sigmoid
  k_gemm_bt<<<dim3(128, 1), 256, 0, stream>>>(o1, Wb_out, out_b, nullptr, (float*)d_out, 16384, 128, 512, 1);
}